// Round 2
// baseline (686.509 us; speedup 1.0000x reference)
//
#include <hip/hip_runtime.h>
#include <hip/hip_bf16.h>

// GAT: N=50000 nodes, E=800000 edges, L=3 layers, H=8 heads, C=16, F=128.
// Runtime dtype detection (data-dependent, graph-capture safe):
//   flags[0]=1 -> float tensors are fp32 (else bf16)
//   flags[1]=1 -> edge_index is int64 (else int32)
// All parameter kernels take ELEMENT offsets; the byte address is formed
// inside the kernel after the dtype flag is known.

#define GAT_F 128
#define GAT_H 8
#define GAT_C 16

__device__ __forceinline__ float bf2f(unsigned short u) {
    union { unsigned int i; float f; } x; x.i = ((unsigned int)u) << 16; return x.f;
}
__device__ __forceinline__ float ldf(const void* p, size_t i, int isf32) {
    return isf32 ? ((const float*)p)[i] : bf2f(((const unsigned short*)p)[i]);
}
__device__ __forceinline__ int ldei(const int* ei, int i, int is64) {
    return is64 ? ei[2 * (size_t)i] : ei[i];
}

// ---------- dtype detection ----------
__global__ void k_detect(const unsigned short* __restrict__ xb,
                         const int* __restrict__ ei, int* flags) {
    __shared__ int nan_cnt, zero_cnt;
    if (threadIdx.x == 0) { nan_cnt = 0; zero_cnt = 0; }
    __syncthreads();
    int t = threadIdx.x;
    int ln = 0;
    for (int i = t; i < 8192; i += 256) {
        unsigned short u = xb[i];
        if ((u & 0x7F80) == 0x7F80) ln++;   // bf16 inf/nan pattern
    }
    int lz = 0;
    for (int i = t; i < 2048; i += 256) {
        if (ei[2 * i + 1] == 0) lz++;       // int64 high words are all zero
    }
    if (ln) atomicAdd(&nan_cnt, ln);
    if (lz) atomicAdd(&zero_cnt, lz);
    __syncthreads();
    if (t == 0) {
        flags[0] = (nan_cnt > 3) ? 1 : 0;     // 1 => fp32 inputs
        flags[1] = (zero_cnt > 1024) ? 1 : 0; // 1 => int64 edge_index
    }
}

// ---------- CSR build ----------
__global__ void k_init_deg(int* deg, int n) {
    int i = blockIdx.x * 256 + threadIdx.x;
    if (i < n) deg[i] = 1;  // self loop
}

__global__ void k_count_deg(const int* __restrict__ ei, int* deg, int E,
                            const int* __restrict__ flags) {
    int k = blockIdx.x * 256 + threadIdx.x;
    int is64 = flags[1];
    if (k < E) atomicAdd(&deg[ldei(ei, E + k, is64)], 1);
}

__global__ void k_scan(const int* __restrict__ deg, int* __restrict__ rowptr, int n) {
    __shared__ int sums[1024];
    int t = threadIdx.x;
    int chunk = (n + 1023) / 1024;
    int s0 = t * chunk, s1 = min(s0 + chunk, n);
    int local = 0;
    for (int i = s0; i < s1; i++) local += deg[i];
    sums[t] = local;
    __syncthreads();
    for (int off = 1; off < 1024; off <<= 1) {
        int v = (t >= off) ? sums[t - off] : 0;
        __syncthreads();
        sums[t] += v;
        __syncthreads();
    }
    int excl = (t == 0) ? 0 : sums[t - 1];
    for (int i = s0; i < s1; i++) { rowptr[i] = excl; excl += deg[i]; }
    if (t == 1023) rowptr[n] = sums[1023];
}

__global__ void k_place_self(const int* __restrict__ rowptr, int* __restrict__ adj,
                             int* __restrict__ cursor, int n) {
    int i = blockIdx.x * 256 + threadIdx.x;
    if (i < n) { adj[rowptr[i]] = i; cursor[i] = 1; }
}

__global__ void k_scatter(const int* __restrict__ ei, const int* __restrict__ rowptr,
                          int* __restrict__ cursor, int* __restrict__ adj, int E,
                          const int* __restrict__ flags) {
    int k = blockIdx.x * 256 + threadIdx.x;
    int is64 = flags[1];
    if (k < E) {
        int s = ldei(ei, k, is64);
        int d = ldei(ei, E + k, is64);
        int p = atomicAdd(&cursor[d], 1);
        adj[rowptr[d] + p] = s;
    }
}

// ---------- per-layer GEMM + attention scores ----------
__global__ __launch_bounds__(256) void k_gemm_scores(
    const void* __restrict__ xin, int x_is_input,
    const void* __restrict__ W, long w_off,        // element offsets
    const void* __restrict__ asrc, const void* __restrict__ adst, long a_off,
    float* __restrict__ hout, float* __restrict__ es, float* __restrict__ ed,
    int n, const int* __restrict__ flags)
{
    __shared__ float xs[32 * 132];  // padded stride 132
    int isf32 = flags[0];
    int t = threadIdx.x;
    int row0 = blockIdx.x * 32;

    for (int i = t; i < 32 * GAT_F; i += 256) {
        int r = i >> 7, k = i & 127;
        int gr = row0 + r;
        float v = 0.f;
        if (gr < n) {
            size_t idx = (size_t)gr * GAT_F + k;
            v = x_is_input ? ldf(xin, idx, isf32) : ((const float*)xin)[idx];
        }
        xs[r * 132 + k] = v;
    }
    __syncthreads();

    int tx = t & 31, ty = t >> 5;
    int r0 = ty * 4, c0 = tx * 4;
    float acc[4][4];
    #pragma unroll
    for (int i = 0; i < 4; i++)
        #pragma unroll
        for (int j = 0; j < 4; j++) acc[i][j] = 0.f;

    if (isf32) {
        const float4* Wg = (const float4*)((const float*)W + w_off);
        for (int k = 0; k < GAT_F; k++) {
            float4 wv = Wg[k * 32 + tx];
            #pragma unroll
            for (int i = 0; i < 4; i++) {
                float xv = xs[(r0 + i) * 132 + k];
                acc[i][0] += xv * wv.x; acc[i][1] += xv * wv.y;
                acc[i][2] += xv * wv.z; acc[i][3] += xv * wv.w;
            }
        }
    } else {
        const ushort4* Wg = (const ushort4*)((const unsigned short*)W + w_off);
        for (int k = 0; k < GAT_F; k++) {
            ushort4 u4 = Wg[k * 32 + tx];
            float4 wv = make_float4(bf2f(u4.x), bf2f(u4.y), bf2f(u4.z), bf2f(u4.w));
            #pragma unroll
            for (int i = 0; i < 4; i++) {
                float xv = xs[(r0 + i) * 132 + k];
                acc[i][0] += xv * wv.x; acc[i][1] += xv * wv.y;
                acc[i][2] += xv * wv.z; acc[i][3] += xv * wv.w;
            }
        }
    }

    int head = tx >> 2;
    int cb = (tx & 3) * 4;
    float av[4], dv[4];
    #pragma unroll
    for (int j = 0; j < 4; j++) {
        av[j] = ldf(asrc, a_off + head * GAT_C + cb + j, isf32);
        dv[j] = ldf(adst, a_off + head * GAT_C + cb + j, isf32);
    }
    #pragma unroll
    for (int i = 0; i < 4; i++) {
        float ps = acc[i][0] * av[0] + acc[i][1] * av[1] + acc[i][2] * av[2] + acc[i][3] * av[3];
        float pd = acc[i][0] * dv[0] + acc[i][1] * dv[1] + acc[i][2] * dv[2] + acc[i][3] * dv[3];
        ps += __shfl_xor(ps, 1); ps += __shfl_xor(ps, 2);
        pd += __shfl_xor(pd, 1); pd += __shfl_xor(pd, 2);
        int gr = row0 + r0 + i;
        if ((tx & 3) == 0 && gr < n) {
            es[(size_t)gr * GAT_H + head] = ps;
            ed[(size_t)gr * GAT_H + head] = pd;
        }
        if (gr < n) {
            *(float4*)(hout + (size_t)gr * GAT_F + c0) =
                make_float4(acc[i][0], acc[i][1], acc[i][2], acc[i][3]);
        }
    }
}

// ---------- aggregation: one wave per node ----------
__global__ __launch_bounds__(256) void k_aggregate(
    const float* __restrict__ h, const float* __restrict__ es, const float* __restrict__ ed,
    const int* __restrict__ rowptr, const int* __restrict__ adj,
    const void* __restrict__ bias, long b_off, float* __restrict__ out, int n,
    const int* __restrict__ flags)
{
    int isf32 = flags[0];
    int lane = threadIdx.x & 63;
    int node = blockIdx.x * 4 + (threadIdx.x >> 6);
    if (node >= n) return;
    int base = rowptr[node];
    int deg = rowptr[node + 1] - base;

    float edv[8];
    {
        float4 a = *(const float4*)(ed + (size_t)node * 8);
        float4 b = *(const float4*)(ed + (size_t)node * 8 + 4);
        edv[0] = a.x; edv[1] = a.y; edv[2] = a.z; edv[3] = a.w;
        edv[4] = b.x; edv[5] = b.y; edv[6] = b.z; edv[7] = b.w;
    }

    float m[8], lsum[8];
    #pragma unroll
    for (int hh = 0; hh < 8; hh++) { m[hh] = -1e30f; lsum[hh] = 0.f; }
    for (int j = lane; j < deg; j += 64) {
        int s = adj[base + j];
        float4 a = *(const float4*)(es + (size_t)s * 8);
        float4 b = *(const float4*)(es + (size_t)s * 8 + 4);
        float ev[8] = {a.x, a.y, a.z, a.w, b.x, b.y, b.z, b.w};
        #pragma unroll
        for (int hh = 0; hh < 8; hh++) {
            float v = ev[hh] + edv[hh];
            v = v > 0.f ? v : 0.2f * v;
            float nm = fmaxf(m[hh], v);
            lsum[hh] = lsum[hh] * __expf(m[hh] - nm) + __expf(v - nm);
            m[hh] = nm;
        }
    }
    #pragma unroll
    for (int hh = 0; hh < 8; hh++) {
        #pragma unroll
        for (int off = 1; off < 64; off <<= 1) {
            float mo = __shfl_xor(m[hh], off);
            float lo = __shfl_xor(lsum[hh], off);
            float nm = fmaxf(m[hh], mo);
            lsum[hh] = lsum[hh] * __expf(m[hh] - nm) + lo * __expf(mo - nm);
            m[hh] = nm;
        }
    }

    int head = lane >> 3;
    int ch = lane << 1;
    float m_mine = m[0], l_mine = lsum[0], ed_mine = edv[0];
    #pragma unroll
    for (int hh = 1; hh < 8; hh++)
        if (head == hh) { m_mine = m[hh]; l_mine = lsum[hh]; ed_mine = edv[hh]; }
    float inv = 1.f / (l_mine + 1e-16f);

    float acc0 = 0.f, acc1 = 0.f;
    for (int j0 = 0; j0 < deg; j0 += 64) {
        int sp = 0;
        if (j0 + lane < deg) sp = adj[base + j0 + lane];
        int lim = min(64, deg - j0);
        for (int j = 0; j < lim; j++) {
            int s = __shfl(sp, j);
            float evv = es[(size_t)s * 8 + head] + ed_mine;
            evv = evv > 0.f ? evv : 0.2f * evv;
            float alpha = __expf(evv - m_mine) * inv;
            float2 hv = *(const float2*)(h + (size_t)s * GAT_F + ch);
            acc0 += alpha * hv.x;
            acc1 += alpha * hv.y;
        }
    }

    float o0 = acc0 + ldf(bias, b_off + ch, isf32);
    float o1 = acc1 + ldf(bias, b_off + ch + 1, isf32);
    o0 = o0 > 0.f ? o0 : (__expf(o0) - 1.f);
    o1 = o1 > 0.f ? o1 : (__expf(o1) - 1.f);
    *(float2*)(out + (size_t)node * GAT_F + ch) = make_float2(o0, o1);
}

// ---------- final FC ----------
__global__ __launch_bounds__(256) void k_fc(
    const float* __restrict__ h, const void* __restrict__ fw,
    const void* __restrict__ fb, void* __restrict__ out, int n,
    const int* __restrict__ flags)
{
    __shared__ float fws[GAT_F * GAT_C];
    int isf32 = flags[0];
    int t = threadIdx.x;
    for (int i = t; i < GAT_F * GAT_C; i += 256)
        fws[i] = ldf(fw, i, isf32);
    __syncthreads();
    int row = blockIdx.x * 256 + t;
    if (row >= n) return;
    float acc[16];
    #pragma unroll
    for (int c = 0; c < 16; c++) acc[c] = ldf(fb, c, isf32);
    const float4* hr = (const float4*)(h + (size_t)row * GAT_F);
    for (int k4 = 0; k4 < GAT_F / 4; k4++) {
        float4 xv = hr[k4];
        float xs4[4] = {xv.x, xv.y, xv.z, xv.w};
        #pragma unroll
        for (int kk = 0; kk < 4; kk++) {
            int k = k4 * 4 + kk;
            const float4* wr = (const float4*)(fws + k * GAT_C);
            #pragma unroll
            for (int c4 = 0; c4 < 4; c4++) {
                float4 wv = wr[c4];
                acc[c4 * 4 + 0] += xs4[kk] * wv.x;
                acc[c4 * 4 + 1] += xs4[kk] * wv.y;
                acc[c4 * 4 + 2] += xs4[kk] * wv.z;
                acc[c4 * 4 + 3] += xs4[kk] * wv.w;
            }
        }
    }
    if (isf32) {
        float* o = (float*)out + (size_t)row * GAT_C;
        #pragma unroll
        for (int c = 0; c < 16; c++) o[c] = acc[c];
    } else {
        __hip_bfloat16* o = (__hip_bfloat16*)out + (size_t)row * GAT_C;
        #pragma unroll
        for (int c = 0; c < 16; c++) o[c] = __float2bfloat16(acc[c]);
    }
}

extern "C" void kernel_launch(void* const* d_in, const int* in_sizes, int n_in,
                              void* d_out, int out_size, void* d_ws, size_t ws_size,
                              hipStream_t stream) {
    const void* x      = d_in[0];
    const void* Ws     = d_in[1];
    const void* att_s  = d_in[2];
    const void* att_d  = d_in[3];
    const void* biases = d_in[4];
    const void* fc_w   = d_in[5];
    const void* fc_b   = d_in[6];
    const int*  ei     = (const int*)d_in[7];

    const int N  = in_sizes[0] / GAT_F;
    const int E  = in_sizes[7] / 2;
    const int L  = in_sizes[1] / (GAT_F * GAT_F);
    const int ET = E + N;

    char* w = (char*)d_ws;
    int* flags  = (int*)w;   w += 64;
    float* hA   = (float*)w; w += (size_t)N * GAT_F * 4;
    float* hB   = (float*)w; w += (size_t)N * GAT_F * 4;
    float* es   = (float*)w; w += (size_t)N * GAT_H * 4;
    float* ed   = (float*)w; w += (size_t)N * GAT_H * 4;
    int* rowptr = (int*)w;   w += (((size_t)(N + 1) * 4 + 15) & ~15ull);
    int* cursor = (int*)w;   w += (size_t)N * 4;
    int* adj    = (int*)w;   w += (size_t)ET * 4;

    int nb_n = (N + 255) / 256;
    int nb_e = (E + 255) / 256;

    k_detect<<<1, 256, 0, stream>>>((const unsigned short*)x, ei, flags);

    k_init_deg<<<nb_n, 256, 0, stream>>>(cursor, N);
    k_count_deg<<<nb_e, 256, 0, stream>>>(ei, cursor, E, flags);
    k_scan<<<1, 1024, 0, stream>>>(cursor, rowptr, N);
    k_place_self<<<nb_n, 256, 0, stream>>>(rowptr, adj, cursor, N);
    k_scatter<<<nb_e, 256, 0, stream>>>(ei, rowptr, cursor, adj, E, flags);

    int nb_g = (N + 31) / 32;
    int nb_a = (N + 3) / 4;
    for (int l = 0; l < L; l++) {
        k_gemm_scores<<<nb_g, 256, 0, stream>>>(
            (l == 0) ? x : (const void*)hA, (l == 0) ? 1 : 0,
            Ws, (long)l * GAT_F * GAT_F,
            att_s, att_d, (long)l * GAT_H * GAT_C,
            hB, es, ed, N, flags);
        k_aggregate<<<nb_a, 256, 0, stream>>>(
            hB, es, ed, rowptr, adj,
            biases, (long)l * GAT_F, hA, N, flags);
    }
    k_fc<<<nb_n, 256, 0, stream>>>(hA, fc_w, fc_b, d_out, N, flags);
}

// Round 3
// 645.739 us; speedup vs baseline: 1.0631x; 1.0631x over previous
//
#include <hip/hip_runtime.h>
#include <hip/hip_bf16.h>

// GAT: N=50000 nodes, E=800000 edges, L=3 layers, H=8 heads, C=16, F=128.
// Runtime dtype detection (data-dependent, graph-capture safe):
//   flags[0]=1 -> float tensors are fp32 (else bf16)
//   flags[1]=1 -> edge_index is int64 (else int32)
// R3: aggregate rewritten — no ds_bpermute (uniform adj loads), 4x edge unroll,
// 32-bit hot-loop addressing, 1/l hoisted, cheaper softmax merge (max-reduce +
// rescale + sum-reduce). adj padded by 8 zeros so the unroll can overread.

#define GAT_F 128
#define GAT_H 8
#define GAT_C 16

__device__ __forceinline__ float bf2f(unsigned short u) {
    union { unsigned int i; float f; } x; x.i = ((unsigned int)u) << 16; return x.f;
}
__device__ __forceinline__ float ldf(const void* p, size_t i, int isf32) {
    return isf32 ? ((const float*)p)[i] : bf2f(((const unsigned short*)p)[i]);
}
__device__ __forceinline__ int ldei(const int* ei, int i, int is64) {
    return is64 ? ei[2 * (size_t)i] : ei[i];
}

// ---------- dtype detection ----------
__global__ void k_detect(const unsigned short* __restrict__ xb,
                         const int* __restrict__ ei, int* flags) {
    __shared__ int nan_cnt, zero_cnt;
    if (threadIdx.x == 0) { nan_cnt = 0; zero_cnt = 0; }
    __syncthreads();
    int t = threadIdx.x;
    int ln = 0;
    for (int i = t; i < 8192; i += 256) {
        unsigned short u = xb[i];
        if ((u & 0x7F80) == 0x7F80) ln++;   // bf16 inf/nan pattern
    }
    int lz = 0;
    for (int i = t; i < 2048; i += 256) {
        if (ei[2 * i + 1] == 0) lz++;       // int64 high words are all zero
    }
    if (ln) atomicAdd(&nan_cnt, ln);
    if (lz) atomicAdd(&zero_cnt, lz);
    __syncthreads();
    if (t == 0) {
        flags[0] = (nan_cnt > 3) ? 1 : 0;     // 1 => fp32 inputs
        flags[1] = (zero_cnt > 1024) ? 1 : 0; // 1 => int64 edge_index
    }
}

// ---------- CSR build ----------
__global__ void k_init_deg(int* deg, int n) {
    int i = blockIdx.x * 256 + threadIdx.x;
    if (i < n) deg[i] = 1;  // self loop
}

__global__ void k_count_deg(const int* __restrict__ ei, int* deg, int E,
                            const int* __restrict__ flags) {
    int k = blockIdx.x * 256 + threadIdx.x;
    int is64 = flags[1];
    if (k < E) atomicAdd(&deg[ldei(ei, E + k, is64)], 1);
}

__global__ void k_scan(const int* __restrict__ deg, int* __restrict__ rowptr, int n) {
    __shared__ int sums[1024];
    int t = threadIdx.x;
    int chunk = (n + 1023) / 1024;
    int s0 = t * chunk, s1 = min(s0 + chunk, n);
    int local = 0;
    for (int i = s0; i < s1; i++) local += deg[i];
    sums[t] = local;
    __syncthreads();
    for (int off = 1; off < 1024; off <<= 1) {
        int v = (t >= off) ? sums[t - off] : 0;
        __syncthreads();
        sums[t] += v;
        __syncthreads();
    }
    int excl = (t == 0) ? 0 : sums[t - 1];
    for (int i = s0; i < s1; i++) { rowptr[i] = excl; excl += deg[i]; }
    if (t == 1023) rowptr[n] = sums[1023];
}

__global__ void k_place_self(const int* __restrict__ rowptr, int* __restrict__ adj,
                             int* __restrict__ cursor, int n) {
    int i = blockIdx.x * 256 + threadIdx.x;
    if (i < n) { adj[rowptr[i]] = i; cursor[i] = 1; }
    if (blockIdx.x == 0 && threadIdx.x < 8) adj[rowptr[n] + threadIdx.x] = 0;  // pad for 4x unroll overread
}

__global__ void k_scatter(const int* __restrict__ ei, const int* __restrict__ rowptr,
                          int* __restrict__ cursor, int* __restrict__ adj, int E,
                          const int* __restrict__ flags) {
    int k = blockIdx.x * 256 + threadIdx.x;
    int is64 = flags[1];
    if (k < E) {
        int s = ldei(ei, k, is64);
        int d = ldei(ei, E + k, is64);
        int p = atomicAdd(&cursor[d], 1);
        adj[rowptr[d] + p] = s;
    }
}

// ---------- per-layer GEMM + attention scores ----------
__global__ __launch_bounds__(256) void k_gemm_scores(
    const void* __restrict__ xin, int x_is_input,
    const void* __restrict__ W, long w_off,        // element offsets
    const void* __restrict__ asrc, const void* __restrict__ adst, long a_off,
    float* __restrict__ hout, float* __restrict__ es, float* __restrict__ ed,
    int n, const int* __restrict__ flags)
{
    __shared__ float xs[32 * 132];  // padded stride 132 floats (528B, 16B-aligned rows)
    int isf32 = flags[0];
    int t = threadIdx.x;
    int row0 = blockIdx.x * 32;

    if (!x_is_input) {
        // fp32 workspace input: float4 staging
        const float4* xg = (const float4*)xin;
        for (int i = t; i < 32 * GAT_F / 4; i += 256) {
            int r = i >> 5, k4 = i & 31;
            int gr = row0 + r;
            float4 v = make_float4(0.f, 0.f, 0.f, 0.f);
            if (gr < n) v = xg[gr * 32 + k4];
            *(float4*)&xs[r * 132 + k4 * 4] = v;
        }
    } else {
        for (int i = t; i < 32 * GAT_F; i += 256) {
            int r = i >> 7, k = i & 127;
            int gr = row0 + r;
            float v = 0.f;
            if (gr < n) v = ldf(xin, (size_t)gr * GAT_F + k, isf32);
            xs[r * 132 + k] = v;
        }
    }
    __syncthreads();

    int tx = t & 31, ty = t >> 5;
    int r0 = ty * 4, c0 = tx * 4;
    float acc[4][4];
    #pragma unroll
    for (int i = 0; i < 4; i++)
        #pragma unroll
        for (int j = 0; j < 4; j++) acc[i][j] = 0.f;

    if (isf32) {
        const float4* Wg = (const float4*)((const float*)W + w_off);
        for (int k = 0; k < GAT_F; k++) {
            float4 wv = Wg[k * 32 + tx];
            #pragma unroll
            for (int i = 0; i < 4; i++) {
                float xv = xs[(r0 + i) * 132 + k];
                acc[i][0] += xv * wv.x; acc[i][1] += xv * wv.y;
                acc[i][2] += xv * wv.z; acc[i][3] += xv * wv.w;
            }
        }
    } else {
        const ushort4* Wg = (const ushort4*)((const unsigned short*)W + w_off);
        for (int k = 0; k < GAT_F; k++) {
            ushort4 u4 = Wg[k * 32 + tx];
            float4 wv = make_float4(bf2f(u4.x), bf2f(u4.y), bf2f(u4.z), bf2f(u4.w));
            #pragma unroll
            for (int i = 0; i < 4; i++) {
                float xv = xs[(r0 + i) * 132 + k];
                acc[i][0] += xv * wv.x; acc[i][1] += xv * wv.y;
                acc[i][2] += xv * wv.z; acc[i][3] += xv * wv.w;
            }
        }
    }

    int head = tx >> 2;
    int cb = (tx & 3) * 4;
    float av[4], dv[4];
    #pragma unroll
    for (int j = 0; j < 4; j++) {
        av[j] = ldf(asrc, a_off + head * GAT_C + cb + j, isf32);
        dv[j] = ldf(adst, a_off + head * GAT_C + cb + j, isf32);
    }
    #pragma unroll
    for (int i = 0; i < 4; i++) {
        float ps = acc[i][0] * av[0] + acc[i][1] * av[1] + acc[i][2] * av[2] + acc[i][3] * av[3];
        float pd = acc[i][0] * dv[0] + acc[i][1] * dv[1] + acc[i][2] * dv[2] + acc[i][3] * dv[3];
        ps += __shfl_xor(ps, 1); ps += __shfl_xor(ps, 2);
        pd += __shfl_xor(pd, 1); pd += __shfl_xor(pd, 2);
        int gr = row0 + r0 + i;
        if ((tx & 3) == 0 && gr < n) {
            es[(size_t)gr * GAT_H + head] = ps;
            ed[(size_t)gr * GAT_H + head] = pd;
        }
        if (gr < n) {
            *(float4*)(hout + (size_t)gr * GAT_F + c0) =
                make_float4(acc[i][0], acc[i][1], acc[i][2], acc[i][3]);
        }
    }
}

// ---------- aggregation: one wave per node ----------
__global__ __launch_bounds__(256) void k_aggregate(
    const float* __restrict__ h, const float* __restrict__ es, const float* __restrict__ ed,
    const int* __restrict__ rowptr, const int* __restrict__ adj,
    const void* __restrict__ bias, long b_off, float* __restrict__ out, int n,
    const int* __restrict__ flags)
{
    int isf32 = flags[0];
    int lane = threadIdx.x & 63;
    int node = blockIdx.x * 4 + (threadIdx.x >> 6);
    if (node >= n) return;
    int base = rowptr[node];
    int deg = rowptr[node + 1] - base;

    const float4* es4 = (const float4*)es;
    const float4* ed4 = (const float4*)ed;

    float edv[8];
    {
        float4 a = ed4[node * 2];
        float4 b = ed4[node * 2 + 1];
        edv[0] = a.x; edv[1] = a.y; edv[2] = a.z; edv[3] = a.w;
        edv[4] = b.x; edv[5] = b.y; edv[6] = b.z; edv[7] = b.w;
    }

    // Pass A: per-lane online softmax stats over lane-strided edges.
    float m[8], lsum[8];
    #pragma unroll
    for (int hh = 0; hh < 8; hh++) { m[hh] = -1e30f; lsum[hh] = 0.f; }
    for (int j = lane; j < deg; j += 64) {
        int s = adj[base + j];
        float4 a = es4[s * 2];
        float4 b = es4[s * 2 + 1];
        float ev[8] = {a.x, a.y, a.z, a.w, b.x, b.y, b.z, b.w};
        #pragma unroll
        for (int hh = 0; hh < 8; hh++) {
            float v = ev[hh] + edv[hh];
            v = v > 0.f ? v : 0.2f * v;
            float nm = fmaxf(m[hh], v);
            lsum[hh] = lsum[hh] * __expf(m[hh] - nm) + __expf(v - nm);
            m[hh] = nm;
        }
    }
    // merge: max-reduce, one rescale, sum-reduce (cheaper than online merge)
    #pragma unroll
    for (int hh = 0; hh < 8; hh++) {
        float M = m[hh];
        #pragma unroll
        for (int off = 1; off < 64; off <<= 1) M = fmaxf(M, __shfl_xor(M, off));
        float ls = lsum[hh] * __expf(m[hh] - M);   // lsum==0 -> 0*0 = 0
        #pragma unroll
        for (int off = 1; off < 64; off <<= 1) ls += __shfl_xor(ls, off);
        m[hh] = M; lsum[hh] = ls;
    }

    int head = lane >> 3;
    int ch2 = lane;  // float2 index within row (=ch/2)
    float m_mine = m[0], l_mine = lsum[0], ed_mine = edv[0];
    #pragma unroll
    for (int hh = 1; hh < 8; hh++)
        if (head == hh) { m_mine = m[hh]; l_mine = lsum[hh]; ed_mine = edv[hh]; }
    float inv = 1.f / (l_mine + 1e-16f);

    // Pass B: uniform adj loads (no shfl), 4x unroll, 32-bit indices,
    // alpha numerator only (1/l applied once at the end).
    const float2* h2 = (const float2*)h;
    float acc0 = 0.f, acc1 = 0.f;
    for (int j0 = 0; j0 < deg; j0 += 4) {
        int sa = adj[base + j0];
        int sb = adj[base + j0 + 1];   // may overread into next node / pad: masked below
        int sc = adj[base + j0 + 2];
        int sd = adj[base + j0 + 3];
        float va = es[sa * 8 + head];
        float vb = es[sb * 8 + head];
        float vc = es[sc * 8 + head];
        float vd = es[sd * 8 + head];
        float2 ha = h2[sa * 64 + ch2];
        float2 hb = h2[sb * 64 + ch2];
        float2 hc = h2[sc * 64 + ch2];
        float2 hd = h2[sd * 64 + ch2];
        va += ed_mine; va = va > 0.f ? va : 0.2f * va;
        vb += ed_mine; vb = vb > 0.f ? vb : 0.2f * vb;
        vc += ed_mine; vc = vc > 0.f ? vc : 0.2f * vc;
        vd += ed_mine; vd = vd > 0.f ? vd : 0.2f * vd;
        float aa = __expf(va - m_mine);
        float ab = (j0 + 1 < deg) ? __expf(vb - m_mine) : 0.f;
        float ac = (j0 + 2 < deg) ? __expf(vc - m_mine) : 0.f;
        float ad = (j0 + 3 < deg) ? __expf(vd - m_mine) : 0.f;
        acc0 += aa * ha.x + ab * hb.x + ac * hc.x + ad * hd.x;
        acc1 += aa * ha.y + ab * hb.y + ac * hc.y + ad * hd.y;
    }

    int ch = lane << 1;
    float o0 = acc0 * inv + ldf(bias, b_off + ch, isf32);
    float o1 = acc1 * inv + ldf(bias, b_off + ch + 1, isf32);
    o0 = o0 > 0.f ? o0 : (__expf(o0) - 1.f);
    o1 = o1 > 0.f ? o1 : (__expf(o1) - 1.f);
    *(float2*)(out + (size_t)node * GAT_F + ch) = make_float2(o0, o1);
}

// ---------- final FC ----------
__global__ __launch_bounds__(256) void k_fc(
    const float* __restrict__ h, const void* __restrict__ fw,
    const void* __restrict__ fb, void* __restrict__ out, int n,
    const int* __restrict__ flags)
{
    __shared__ float fws[GAT_F * GAT_C];
    int isf32 = flags[0];
    int t = threadIdx.x;
    for (int i = t; i < GAT_F * GAT_C; i += 256)
        fws[i] = ldf(fw, i, isf32);
    __syncthreads();
    int row = blockIdx.x * 256 + t;
    if (row >= n) return;
    float acc[16];
    #pragma unroll
    for (int c = 0; c < 16; c++) acc[c] = ldf(fb, c, isf32);
    const float4* hr = (const float4*)(h + (size_t)row * GAT_F);
    for (int k4 = 0; k4 < GAT_F / 4; k4++) {
        float4 xv = hr[k4];
        float xs4[4] = {xv.x, xv.y, xv.z, xv.w};
        #pragma unroll
        for (int kk = 0; kk < 4; kk++) {
            int k = k4 * 4 + kk;
            const float4* wr = (const float4*)(fws + k * GAT_C);
            #pragma unroll
            for (int c4 = 0; c4 < 4; c4++) {
                float4 wv = wr[c4];
                acc[c4 * 4 + 0] += xs4[kk] * wv.x;
                acc[c4 * 4 + 1] += xs4[kk] * wv.y;
                acc[c4 * 4 + 2] += xs4[kk] * wv.z;
                acc[c4 * 4 + 3] += xs4[kk] * wv.w;
            }
        }
    }
    if (isf32) {
        float* o = (float*)out + (size_t)row * GAT_C;
        #pragma unroll
        for (int c = 0; c < 16; c++) o[c] = acc[c];
    } else {
        __hip_bfloat16* o = (__hip_bfloat16*)out + (size_t)row * GAT_C;
        #pragma unroll
        for (int c = 0; c < 16; c++) o[c] = __float2bfloat16(acc[c]);
    }
}

extern "C" void kernel_launch(void* const* d_in, const int* in_sizes, int n_in,
                              void* d_out, int out_size, void* d_ws, size_t ws_size,
                              hipStream_t stream) {
    const void* x      = d_in[0];
    const void* Ws     = d_in[1];
    const void* att_s  = d_in[2];
    const void* att_d  = d_in[3];
    const void* biases = d_in[4];
    const void* fc_w   = d_in[5];
    const void* fc_b   = d_in[6];
    const int*  ei     = (const int*)d_in[7];

    const int N  = in_sizes[0] / GAT_F;
    const int E  = in_sizes[7] / 2;
    const int L  = in_sizes[1] / (GAT_F * GAT_F);
    const int ET = E + N;

    char* w = (char*)d_ws;
    int* flags  = (int*)w;   w += 64;
    float* hA   = (float*)w; w += (size_t)N * GAT_F * 4;
    float* hB   = (float*)w; w += (size_t)N * GAT_F * 4;
    float* es   = (float*)w; w += (size_t)N * GAT_H * 4;
    float* ed   = (float*)w; w += (size_t)N * GAT_H * 4;
    int* rowptr = (int*)w;   w += (((size_t)(N + 1) * 4 + 15) & ~15ull);
    int* cursor = (int*)w;   w += (size_t)N * 4;
    int* adj    = (int*)w;   w += (size_t)(ET + 16) * 4;   // +pad for unroll overread

    int nb_n = (N + 255) / 256;
    int nb_e = (E + 255) / 256;

    k_detect<<<1, 256, 0, stream>>>((const unsigned short*)x, ei, flags);

    k_init_deg<<<nb_n, 256, 0, stream>>>(cursor, N);
    k_count_deg<<<nb_e, 256, 0, stream>>>(ei, cursor, E, flags);
    k_scan<<<1, 1024, 0, stream>>>(cursor, rowptr, N);
    k_place_self<<<nb_n, 256, 0, stream>>>(rowptr, adj, cursor, N);
    k_scatter<<<nb_e, 256, 0, stream>>>(ei, rowptr, cursor, adj, E, flags);

    int nb_g = (N + 31) / 32;
    int nb_a = (N + 3) / 4;
    for (int l = 0; l < L; l++) {
        k_gemm_scores<<<nb_g, 256, 0, stream>>>(
            (l == 0) ? x : (const void*)hA, (l == 0) ? 1 : 0,
            Ws, (long)l * GAT_F * GAT_F,
            att_s, att_d, (long)l * GAT_H * GAT_C,
            hB, es, ed, N, flags);
        k_aggregate<<<nb_a, 256, 0, stream>>>(
            hB, es, ed, rowptr, adj,
            biases, (long)l * GAT_F, hA, N, flags);
    }
    k_fc<<<nb_n, 256, 0, stream>>>(hA, fc_w, fc_b, d_out, N, flags);
}

// Round 4
// 530.231 us; speedup vs baseline: 1.2947x; 1.2178x over previous
//
#include <hip/hip_runtime.h>
#include <hip/hip_bf16.h>

// GAT: N=50000 nodes, E=800000 edges, L=3 layers, H=8 heads, C=16, F=128.
// Runtime dtype detection (data-dependent, graph-capture safe):
//   flags[0]=1 -> float tensors are fp32 (else bf16)
//   flags[1]=1 -> edge_index is int64 (else int32)
// R4: single-pass aggregate (no max-subtraction: scores are bounded, exp can't
// overflow fp32; softmax identical without the shift). h stored as packed
// bf16x2 -> 256B/edge gather instead of 512B. No cross-lane merge at all:
// every lane walks every edge of its node, so per-head l replicates for free.

#define GAT_F 128
#define GAT_H 8
#define GAT_C 16

__device__ __forceinline__ float bf2f(unsigned short u) {
    union { unsigned int i; float f; } x; x.i = ((unsigned int)u) << 16; return x.f;
}
__device__ __forceinline__ float bfhi2f(unsigned int u) {   // high 16 bits as bf16
    union { unsigned int i; float f; } x; x.i = u & 0xFFFF0000u; return x.f;
}
__device__ __forceinline__ float bflo2f(unsigned int u) {   // low 16 bits as bf16
    union { unsigned int i; float f; } x; x.i = u << 16; return x.f;
}
__device__ __forceinline__ unsigned int pk_bf16(float a, float b) {  // rne pack
    union { float f; unsigned int i; } ua, ub;
    ua.f = a; ub.f = b;
    unsigned int ra = (ua.i + 0x7FFFu + ((ua.i >> 16) & 1u)) >> 16;
    unsigned int rb = (ub.i + 0x7FFFu + ((ub.i >> 16) & 1u)) & 0xFFFF0000u;
    return ra | rb;
}
__device__ __forceinline__ float ldf(const void* p, size_t i, int isf32) {
    return isf32 ? ((const float*)p)[i] : bf2f(((const unsigned short*)p)[i]);
}
__device__ __forceinline__ int ldei(const int* ei, int i, int is64) {
    return is64 ? ei[2 * (size_t)i] : ei[i];
}

// ---------- dtype detection ----------
__global__ void k_detect(const unsigned short* __restrict__ xb,
                         const int* __restrict__ ei, int* flags) {
    __shared__ int nan_cnt, zero_cnt;
    if (threadIdx.x == 0) { nan_cnt = 0; zero_cnt = 0; }
    __syncthreads();
    int t = threadIdx.x;
    int ln = 0;
    for (int i = t; i < 8192; i += 256) {
        unsigned short u = xb[i];
        if ((u & 0x7F80) == 0x7F80) ln++;   // bf16 inf/nan pattern
    }
    int lz = 0;
    for (int i = t; i < 2048; i += 256) {
        if (ei[2 * i + 1] == 0) lz++;       // int64 high words are all zero
    }
    if (ln) atomicAdd(&nan_cnt, ln);
    if (lz) atomicAdd(&zero_cnt, lz);
    __syncthreads();
    if (t == 0) {
        flags[0] = (nan_cnt > 3) ? 1 : 0;     // 1 => fp32 inputs
        flags[1] = (zero_cnt > 1024) ? 1 : 0; // 1 => int64 edge_index
    }
}

// ---------- CSR build ----------
__global__ void k_init_deg(int* deg, int n) {
    int i = blockIdx.x * 256 + threadIdx.x;
    if (i < n) deg[i] = 1;  // self loop
}

__global__ void k_count_deg(const int* __restrict__ ei, int* deg, int E,
                            const int* __restrict__ flags) {
    int k = blockIdx.x * 256 + threadIdx.x;
    int is64 = flags[1];
    if (k < E) atomicAdd(&deg[ldei(ei, E + k, is64)], 1);
}

__global__ void k_scan(const int* __restrict__ deg, int* __restrict__ rowptr, int n) {
    __shared__ int sums[1024];
    int t = threadIdx.x;
    int chunk = (n + 1023) / 1024;
    int s0 = t * chunk, s1 = min(s0 + chunk, n);
    int local = 0;
    for (int i = s0; i < s1; i++) local += deg[i];
    sums[t] = local;
    __syncthreads();
    for (int off = 1; off < 1024; off <<= 1) {
        int v = (t >= off) ? sums[t - off] : 0;
        __syncthreads();
        sums[t] += v;
        __syncthreads();
    }
    int excl = (t == 0) ? 0 : sums[t - 1];
    for (int i = s0; i < s1; i++) { rowptr[i] = excl; excl += deg[i]; }
    if (t == 1023) rowptr[n] = sums[1023];
}

__global__ void k_place_self(const int* __restrict__ rowptr, int* __restrict__ adj,
                             int* __restrict__ cursor, int n) {
    int i = blockIdx.x * 256 + threadIdx.x;
    if (i < n) { adj[rowptr[i]] = i; cursor[i] = 1; }
    if (blockIdx.x == 0 && threadIdx.x < 8) adj[rowptr[n] + threadIdx.x] = 0;  // pad for 4x unroll
}

__global__ void k_scatter(const int* __restrict__ ei, const int* __restrict__ rowptr,
                          int* __restrict__ cursor, int* __restrict__ adj, int E,
                          const int* __restrict__ flags) {
    int k = blockIdx.x * 256 + threadIdx.x;
    int is64 = flags[1];
    if (k < E) {
        int s = ldei(ei, k, is64);
        int d = ldei(ei, E + k, is64);
        int p = atomicAdd(&cursor[d], 1);
        adj[rowptr[d] + p] = s;
    }
}

// ---------- per-layer GEMM + attention scores ----------
// hout: packed bf16x2, row stride 64 dwords (256B/row).
__global__ __launch_bounds__(256) void k_gemm_scores(
    const void* __restrict__ xin, int x_is_input,
    const void* __restrict__ W, long w_off,        // element offsets
    const void* __restrict__ asrc, const void* __restrict__ adst, long a_off,
    unsigned int* __restrict__ hout, float* __restrict__ es, float* __restrict__ ed,
    int n, const int* __restrict__ flags)
{
    __shared__ float xs[32 * 132];  // padded stride 132 floats
    int isf32 = flags[0];
    int t = threadIdx.x;
    int row0 = blockIdx.x * 32;

    if (!x_is_input) {
        const float4* xg = (const float4*)xin;
        for (int i = t; i < 32 * GAT_F / 4; i += 256) {
            int r = i >> 5, k4 = i & 31;
            int gr = row0 + r;
            float4 v = make_float4(0.f, 0.f, 0.f, 0.f);
            if (gr < n) v = xg[gr * 32 + k4];
            *(float4*)&xs[r * 132 + k4 * 4] = v;
        }
    } else {
        for (int i = t; i < 32 * GAT_F; i += 256) {
            int r = i >> 7, k = i & 127;
            int gr = row0 + r;
            float v = 0.f;
            if (gr < n) v = ldf(xin, (size_t)gr * GAT_F + k, isf32);
            xs[r * 132 + k] = v;
        }
    }
    __syncthreads();

    int tx = t & 31, ty = t >> 5;
    int r0 = ty * 4, c0 = tx * 4;
    float acc[4][4];
    #pragma unroll
    for (int i = 0; i < 4; i++)
        #pragma unroll
        for (int j = 0; j < 4; j++) acc[i][j] = 0.f;

    if (isf32) {
        const float4* Wg = (const float4*)((const float*)W + w_off);
        for (int k = 0; k < GAT_F; k++) {
            float4 wv = Wg[k * 32 + tx];
            #pragma unroll
            for (int i = 0; i < 4; i++) {
                float xv = xs[(r0 + i) * 132 + k];
                acc[i][0] += xv * wv.x; acc[i][1] += xv * wv.y;
                acc[i][2] += xv * wv.z; acc[i][3] += xv * wv.w;
            }
        }
    } else {
        const ushort4* Wg = (const ushort4*)((const unsigned short*)W + w_off);
        for (int k = 0; k < GAT_F; k++) {
            ushort4 u4 = Wg[k * 32 + tx];
            float4 wv = make_float4(bf2f(u4.x), bf2f(u4.y), bf2f(u4.z), bf2f(u4.w));
            #pragma unroll
            for (int i = 0; i < 4; i++) {
                float xv = xs[(r0 + i) * 132 + k];
                acc[i][0] += xv * wv.x; acc[i][1] += xv * wv.y;
                acc[i][2] += xv * wv.z; acc[i][3] += xv * wv.w;
            }
        }
    }

    int head = tx >> 2;
    int cb = (tx & 3) * 4;
    float av[4], dv[4];
    #pragma unroll
    for (int j = 0; j < 4; j++) {
        av[j] = ldf(asrc, a_off + head * GAT_C + cb + j, isf32);
        dv[j] = ldf(adst, a_off + head * GAT_C + cb + j, isf32);
    }
    #pragma unroll
    for (int i = 0; i < 4; i++) {
        float ps = acc[i][0] * av[0] + acc[i][1] * av[1] + acc[i][2] * av[2] + acc[i][3] * av[3];
        float pd = acc[i][0] * dv[0] + acc[i][1] * dv[1] + acc[i][2] * dv[2] + acc[i][3] * dv[3];
        ps += __shfl_xor(ps, 1); ps += __shfl_xor(ps, 2);
        pd += __shfl_xor(pd, 1); pd += __shfl_xor(pd, 2);
        int gr = row0 + r0 + i;
        if ((tx & 3) == 0 && gr < n) {
            es[(size_t)gr * GAT_H + head] = ps;
            ed[(size_t)gr * GAT_H + head] = pd;
        }
        if (gr < n) {
            uint2 packed = make_uint2(pk_bf16(acc[i][0], acc[i][1]),
                                      pk_bf16(acc[i][2], acc[i][3]));
            *(uint2*)(hout + gr * 64 + (c0 >> 1)) = packed;
        }
    }
}

// ---------- aggregation: one wave per node, single pass, no max-shift ----------
__global__ __launch_bounds__(256) void k_aggregate(
    const unsigned int* __restrict__ hb,   // packed bf16x2, stride 64 dwords
    const float* __restrict__ es, const float* __restrict__ ed,
    const int* __restrict__ rowptr, const int* __restrict__ adj,
    const void* __restrict__ bias, long b_off, float* __restrict__ out, int n,
    const int* __restrict__ flags)
{
    int isf32 = flags[0];
    int lane = threadIdx.x & 63;
    int node = blockIdx.x * 4 + (threadIdx.x >> 6);
    if (node >= n) return;
    int base = rowptr[node];
    int deg = rowptr[node + 1] - base;
    int head = lane >> 3;
    float edv = ed[node * 8 + head];

    float acc0 = 0.f, acc1 = 0.f, lsum = 0.f;
    for (int j0 = 0; j0 < deg; j0 += 4) {
        int sa = adj[base + j0];
        int sb = adj[base + j0 + 1];   // padded adj: overread safe, masked below
        int sc = adj[base + j0 + 2];
        int sd = adj[base + j0 + 3];
        float va = es[sa * 8 + head] + edv;
        float vb = es[sb * 8 + head] + edv;
        float vc = es[sc * 8 + head] + edv;
        float vd = es[sd * 8 + head] + edv;
        unsigned int ha = hb[sa * 64 + lane];
        unsigned int hbv = hb[sb * 64 + lane];
        unsigned int hc = hb[sc * 64 + lane];
        unsigned int hd = hb[sd * 64 + lane];
        va = va > 0.f ? va : 0.2f * va;
        vb = vb > 0.f ? vb : 0.2f * vb;
        vc = vc > 0.f ? vc : 0.2f * vc;
        vd = vd > 0.f ? vd : 0.2f * vd;
        float pa = __expf(va);                           // bounded scores: no overflow
        float pb = (j0 + 1 < deg) ? __expf(vb) : 0.f;
        float pc = (j0 + 2 < deg) ? __expf(vc) : 0.f;
        float pd = (j0 + 3 < deg) ? __expf(vd) : 0.f;
        lsum += (pa + pb) + (pc + pd);
        acc0 += pa * bflo2f(ha) + pb * bflo2f(hbv) + pc * bflo2f(hc) + pd * bflo2f(hd);
        acc1 += pa * bfhi2f(ha) + pb * bfhi2f(hbv) + pc * bfhi2f(hc) + pd * bfhi2f(hd);
    }

    float inv = 1.f / (lsum + 1e-16f);
    int ch = lane << 1;
    float o0 = acc0 * inv + ldf(bias, b_off + ch, isf32);
    float o1 = acc1 * inv + ldf(bias, b_off + ch + 1, isf32);
    o0 = o0 > 0.f ? o0 : (__expf(o0) - 1.f);
    o1 = o1 > 0.f ? o1 : (__expf(o1) - 1.f);
    *(float2*)(out + (size_t)node * GAT_F + ch) = make_float2(o0, o1);
}

// ---------- final FC ----------
__global__ __launch_bounds__(256) void k_fc(
    const float* __restrict__ h, const void* __restrict__ fw,
    const void* __restrict__ fb, void* __restrict__ out, int n,
    const int* __restrict__ flags)
{
    __shared__ float fws[GAT_F * GAT_C];
    int isf32 = flags[0];
    int t = threadIdx.x;
    for (int i = t; i < GAT_F * GAT_C; i += 256)
        fws[i] = ldf(fw, i, isf32);
    __syncthreads();
    int row = blockIdx.x * 256 + t;
    if (row >= n) return;
    float acc[16];
    #pragma unroll
    for (int c = 0; c < 16; c++) acc[c] = ldf(fb, c, isf32);
    const float4* hr = (const float4*)(h + (size_t)row * GAT_F);
    for (int k4 = 0; k4 < GAT_F / 4; k4++) {
        float4 xv = hr[k4];
        float xs4[4] = {xv.x, xv.y, xv.z, xv.w};
        #pragma unroll
        for (int kk = 0; kk < 4; kk++) {
            int k = k4 * 4 + kk;
            const float4* wr = (const float4*)(fws + k * GAT_C);
            #pragma unroll
            for (int c4 = 0; c4 < 4; c4++) {
                float4 wv = wr[c4];
                acc[c4 * 4 + 0] += xs4[kk] * wv.x;
                acc[c4 * 4 + 1] += xs4[kk] * wv.y;
                acc[c4 * 4 + 2] += xs4[kk] * wv.z;
                acc[c4 * 4 + 3] += xs4[kk] * wv.w;
            }
        }
    }
    if (isf32) {
        float* o = (float*)out + (size_t)row * GAT_C;
        #pragma unroll
        for (int c = 0; c < 16; c++) o[c] = acc[c];
    } else {
        __hip_bfloat16* o = (__hip_bfloat16*)out + (size_t)row * GAT_C;
        #pragma unroll
        for (int c = 0; c < 16; c++) o[c] = __float2bfloat16(acc[c]);
    }
}

extern "C" void kernel_launch(void* const* d_in, const int* in_sizes, int n_in,
                              void* d_out, int out_size, void* d_ws, size_t ws_size,
                              hipStream_t stream) {
    const void* x      = d_in[0];
    const void* Ws     = d_in[1];
    const void* att_s  = d_in[2];
    const void* att_d  = d_in[3];
    const void* biases = d_in[4];
    const void* fc_w   = d_in[5];
    const void* fc_b   = d_in[6];
    const int*  ei     = (const int*)d_in[7];

    const int N  = in_sizes[0] / GAT_F;
    const int E  = in_sizes[7] / 2;
    const int L  = in_sizes[1] / (GAT_F * GAT_F);
    const int ET = E + N;

    char* w = (char*)d_ws;
    int* flags        = (int*)w;          w += 64;
    float* hA         = (float*)w;        w += (size_t)N * GAT_F * 4;   // fp32 agg out / next input
    unsigned int* hB  = (unsigned int*)w; w += (size_t)N * 64 * 4;      // packed bf16 gemm out
    float* es         = (float*)w;        w += (size_t)N * GAT_H * 4;
    float* ed         = (float*)w;        w += (size_t)N * GAT_H * 4;
    int* rowptr       = (int*)w;          w += (((size_t)(N + 1) * 4 + 15) & ~15ull);
    int* cursor       = (int*)w;          w += (size_t)N * 4;
    int* adj          = (int*)w;          w += (size_t)(ET + 16) * 4;

    int nb_n = (N + 255) / 256;
    int nb_e = (E + 255) / 256;

    k_detect<<<1, 256, 0, stream>>>((const unsigned short*)x, ei, flags);

    k_init_deg<<<nb_n, 256, 0, stream>>>(cursor, N);
    k_count_deg<<<nb_e, 256, 0, stream>>>(ei, cursor, E, flags);
    k_scan<<<1, 1024, 0, stream>>>(cursor, rowptr, N);
    k_place_self<<<nb_n, 256, 0, stream>>>(rowptr, adj, cursor, N);
    k_scatter<<<nb_e, 256, 0, stream>>>(ei, rowptr, cursor, adj, E, flags);

    int nb_g = (N + 31) / 32;
    int nb_a = (N + 3) / 4;
    for (int l = 0; l < L; l++) {
        k_gemm_scores<<<nb_g, 256, 0, stream>>>(
            (l == 0) ? x : (const void*)hA, (l == 0) ? 1 : 0,
            Ws, (long)l * GAT_F * GAT_F,
            att_s, att_d, (long)l * GAT_H * GAT_C,
            hB, es, ed, N, flags);
        k_aggregate<<<nb_a, 256, 0, stream>>>(
            hB, es, ed, rowptr, adj,
            biases, (long)l * GAT_F, hA, N, flags);
    }
    k_fc<<<nb_n, 256, 0, stream>>>(hA, fc_w, fc_b, d_out, N, flags);
}

// Round 5
// 459.316 us; speedup vs baseline: 1.4946x; 1.1544x over previous
//
#include <hip/hip_runtime.h>
#include <hip/hip_bf16.h>

// GAT: N=50000 nodes, E=800000 edges, L=3 layers, H=8 heads, C=16, F=128.
// Runtime dtype detection (data-dependent, graph-capture safe):
//   flags[0]=1 -> float tensors are fp32 (else bf16)
//   flags[1]=1 -> edge_index is int64 (else int32)
// R5: hierarchical 3-stage prefix scan (49 blocks) replaces the 77us
// single-block scan; place_self fused into the offset-add stage.

#define GAT_F 128
#define GAT_H 8
#define GAT_C 16

__device__ __forceinline__ float bf2f(unsigned short u) {
    union { unsigned int i; float f; } x; x.i = ((unsigned int)u) << 16; return x.f;
}
__device__ __forceinline__ float bfhi2f(unsigned int u) {
    union { unsigned int i; float f; } x; x.i = u & 0xFFFF0000u; return x.f;
}
__device__ __forceinline__ float bflo2f(unsigned int u) {
    union { unsigned int i; float f; } x; x.i = u << 16; return x.f;
}
__device__ __forceinline__ unsigned int pk_bf16(float a, float b) {  // rne pack
    union { float f; unsigned int i; } ua, ub;
    ua.f = a; ub.f = b;
    unsigned int ra = (ua.i + 0x7FFFu + ((ua.i >> 16) & 1u)) >> 16;
    unsigned int rb = (ub.i + 0x7FFFu + ((ub.i >> 16) & 1u)) & 0xFFFF0000u;
    return ra | rb;
}
__device__ __forceinline__ float ldf(const void* p, size_t i, int isf32) {
    return isf32 ? ((const float*)p)[i] : bf2f(((const unsigned short*)p)[i]);
}
__device__ __forceinline__ int ldei(const int* ei, int i, int is64) {
    return is64 ? ei[2 * (size_t)i] : ei[i];
}

// ---------- dtype detection ----------
__global__ void k_detect(const unsigned short* __restrict__ xb,
                         const int* __restrict__ ei, int* flags) {
    __shared__ int nan_cnt, zero_cnt;
    if (threadIdx.x == 0) { nan_cnt = 0; zero_cnt = 0; }
    __syncthreads();
    int t = threadIdx.x;
    int ln = 0;
    for (int i = t; i < 8192; i += 256) {
        unsigned short u = xb[i];
        if ((u & 0x7F80) == 0x7F80) ln++;   // bf16 inf/nan pattern
    }
    int lz = 0;
    for (int i = t; i < 2048; i += 256) {
        if (ei[2 * i + 1] == 0) lz++;       // int64 high words are all zero
    }
    if (ln) atomicAdd(&nan_cnt, ln);
    if (lz) atomicAdd(&zero_cnt, lz);
    __syncthreads();
    if (t == 0) {
        flags[0] = (nan_cnt > 3) ? 1 : 0;     // 1 => fp32 inputs
        flags[1] = (zero_cnt > 1024) ? 1 : 0; // 1 => int64 edge_index
    }
}

// ---------- CSR build ----------
__global__ void k_init_deg(int* deg, int n) {
    int i = blockIdx.x * 256 + threadIdx.x;
    if (i < n) deg[i] = 1;  // self loop
}

__global__ void k_count_deg(const int* __restrict__ ei, int* deg, int E,
                            const int* __restrict__ flags) {
    int k = blockIdx.x * 256 + threadIdx.x;
    int is64 = flags[1];
    if (k < E) atomicAdd(&deg[ldei(ei, E + k, is64)], 1);
}

// Stage 1: block-local exclusive scan of deg (1024 elems/block), in-place into
// rowptr (block-local values), block total into bsum[b].
__global__ __launch_bounds__(256) void k_scan_blk(
    const int* __restrict__ deg, int* __restrict__ rp_local,
    int* __restrict__ bsum, int n)
{
    int b = blockIdx.x, t = threadIdx.x;
    int i0 = b * 1024 + t * 4;
    int v0 = 0, v1 = 0, v2 = 0, v3 = 0;
    if (i0 + 3 < n) {
        int4 d = *(const int4*)(deg + i0);
        v0 = d.x; v1 = d.y; v2 = d.z; v3 = d.w;
    } else {
        if (i0     < n) v0 = deg[i0];
        if (i0 + 1 < n) v1 = deg[i0 + 1];
        if (i0 + 2 < n) v2 = deg[i0 + 2];
        if (i0 + 3 < n) v3 = deg[i0 + 3];
    }
    int s = v0 + v1 + v2 + v3;
    int lane = t & 63, wid = t >> 6;
    int sc = s;   // inclusive wave scan
    #pragma unroll
    for (int off = 1; off < 64; off <<= 1) {
        int o = __shfl_up(sc, off);
        if (lane >= off) sc += o;
    }
    __shared__ int wsum[4];
    if (lane == 63) wsum[wid] = sc;
    __syncthreads();
    int woff = 0;
    #pragma unroll
    for (int w2 = 0; w2 < 4; w2++) if (w2 < wid) woff += wsum[w2];
    int excl = woff + sc - s;
    if (i0     < n) rp_local[i0]     = excl;
    if (i0 + 1 < n) rp_local[i0 + 1] = excl + v0;
    if (i0 + 2 < n) rp_local[i0 + 2] = excl + v0 + v1;
    if (i0 + 3 < n) rp_local[i0 + 3] = excl + v0 + v1 + v2;
    if (t == 255) bsum[b] = woff + sc;   // block total
}

// Stage 2: exclusive scan of up to 1024 block sums; writes total to rowptr[n].
__global__ __launch_bounds__(256) void k_scan_top(
    int* __restrict__ bsum, int* __restrict__ rowptr, int nb, int n)
{
    __shared__ int sh[1024];
    int t = threadIdx.x;
    for (int i = t; i < 1024; i += 256) sh[i] = (i < nb) ? bsum[i] : 0;
    __syncthreads();
    for (int off = 1; off < 1024; off <<= 1) {
        int vals[4];
        #pragma unroll
        for (int k = 0; k < 4; k++) {
            int i = t + 256 * k;
            vals[k] = (i >= off) ? sh[i - off] : 0;
        }
        __syncthreads();
        #pragma unroll
        for (int k = 0; k < 4; k++) sh[t + 256 * k] += vals[k];
        __syncthreads();
    }
    for (int i = t; i < nb; i += 256) bsum[i] = (i == 0) ? 0 : sh[i - 1];
    if (t == 0) rowptr[n] = sh[nb - 1];
}

// Stage 3: add block offsets (in-place), place self-loop, init cursor, pad adj.
__global__ void k_place_add(int* __restrict__ rowptr, const int* __restrict__ bsum,
                            int* __restrict__ adj, int* __restrict__ cursor, int n)
{
    int i = blockIdx.x * 256 + threadIdx.x;
    if (i < n) {
        int r = rowptr[i] + bsum[i >> 10];
        rowptr[i] = r;
        adj[r] = i;
        cursor[i] = 1;
    }
    if (blockIdx.x == 0 && threadIdx.x < 8) adj[rowptr[n] + threadIdx.x] = 0;  // pad
}

__global__ void k_scatter(const int* __restrict__ ei, const int* __restrict__ rowptr,
                          int* __restrict__ cursor, int* __restrict__ adj, int E,
                          const int* __restrict__ flags) {
    int k = blockIdx.x * 256 + threadIdx.x;
    int is64 = flags[1];
    if (k < E) {
        int s = ldei(ei, k, is64);
        int d = ldei(ei, E + k, is64);
        int p = atomicAdd(&cursor[d], 1);
        adj[rowptr[d] + p] = s;
    }
}

// ---------- per-layer GEMM + attention scores ----------
// hout: packed bf16x2, row stride 64 dwords (256B/row).
__global__ __launch_bounds__(256) void k_gemm_scores(
    const void* __restrict__ xin, int x_is_input,
    const void* __restrict__ W, long w_off,        // element offsets
    const void* __restrict__ asrc, const void* __restrict__ adst, long a_off,
    unsigned int* __restrict__ hout, float* __restrict__ es, float* __restrict__ ed,
    int n, const int* __restrict__ flags)
{
    __shared__ float xs[32 * 132];  // padded stride 132 floats
    int isf32 = flags[0];
    int t = threadIdx.x;
    int row0 = blockIdx.x * 32;

    if (!x_is_input) {
        const float4* xg = (const float4*)xin;
        for (int i = t; i < 32 * GAT_F / 4; i += 256) {
            int r = i >> 5, k4 = i & 31;
            int gr = row0 + r;
            float4 v = make_float4(0.f, 0.f, 0.f, 0.f);
            if (gr < n) v = xg[gr * 32 + k4];
            *(float4*)&xs[r * 132 + k4 * 4] = v;
        }
    } else {
        for (int i = t; i < 32 * GAT_F; i += 256) {
            int r = i >> 7, k = i & 127;
            int gr = row0 + r;
            float v = 0.f;
            if (gr < n) v = ldf(xin, (size_t)gr * GAT_F + k, isf32);
            xs[r * 132 + k] = v;
        }
    }
    __syncthreads();

    int tx = t & 31, ty = t >> 5;
    int r0 = ty * 4, c0 = tx * 4;
    float acc[4][4];
    #pragma unroll
    for (int i = 0; i < 4; i++)
        #pragma unroll
        for (int j = 0; j < 4; j++) acc[i][j] = 0.f;

    if (isf32) {
        const float4* Wg = (const float4*)((const float*)W + w_off);
        for (int k = 0; k < GAT_F; k++) {
            float4 wv = Wg[k * 32 + tx];
            #pragma unroll
            for (int i = 0; i < 4; i++) {
                float xv = xs[(r0 + i) * 132 + k];
                acc[i][0] += xv * wv.x; acc[i][1] += xv * wv.y;
                acc[i][2] += xv * wv.z; acc[i][3] += xv * wv.w;
            }
        }
    } else {
        const ushort4* Wg = (const ushort4*)((const unsigned short*)W + w_off);
        for (int k = 0; k < GAT_F; k++) {
            ushort4 u4 = Wg[k * 32 + tx];
            float4 wv = make_float4(bf2f(u4.x), bf2f(u4.y), bf2f(u4.z), bf2f(u4.w));
            #pragma unroll
            for (int i = 0; i < 4; i++) {
                float xv = xs[(r0 + i) * 132 + k];
                acc[i][0] += xv * wv.x; acc[i][1] += xv * wv.y;
                acc[i][2] += xv * wv.z; acc[i][3] += xv * wv.w;
            }
        }
    }

    int head = tx >> 2;
    int cb = (tx & 3) * 4;
    float av[4], dv[4];
    #pragma unroll
    for (int j = 0; j < 4; j++) {
        av[j] = ldf(asrc, a_off + head * GAT_C + cb + j, isf32);
        dv[j] = ldf(adst, a_off + head * GAT_C + cb + j, isf32);
    }
    #pragma unroll
    for (int i = 0; i < 4; i++) {
        float ps = acc[i][0] * av[0] + acc[i][1] * av[1] + acc[i][2] * av[2] + acc[i][3] * av[3];
        float pd = acc[i][0] * dv[0] + acc[i][1] * dv[1] + acc[i][2] * dv[2] + acc[i][3] * dv[3];
        ps += __shfl_xor(ps, 1); ps += __shfl_xor(ps, 2);
        pd += __shfl_xor(pd, 1); pd += __shfl_xor(pd, 2);
        int gr = row0 + r0 + i;
        if ((tx & 3) == 0 && gr < n) {
            es[(size_t)gr * GAT_H + head] = ps;
            ed[(size_t)gr * GAT_H + head] = pd;
        }
        if (gr < n) {
            uint2 packed = make_uint2(pk_bf16(acc[i][0], acc[i][1]),
                                      pk_bf16(acc[i][2], acc[i][3]));
            *(uint2*)(hout + gr * 64 + (c0 >> 1)) = packed;
        }
    }
}

// ---------- aggregation: one wave per node, single pass, no max-shift ----------
__global__ __launch_bounds__(256) void k_aggregate(
    const unsigned int* __restrict__ hb,   // packed bf16x2, stride 64 dwords
    const float* __restrict__ es, const float* __restrict__ ed,
    const int* __restrict__ rowptr, const int* __restrict__ adj,
    const void* __restrict__ bias, long b_off, float* __restrict__ out, int n,
    const int* __restrict__ flags)
{
    int isf32 = flags[0];
    int lane = threadIdx.x & 63;
    int node = blockIdx.x * 4 + (threadIdx.x >> 6);
    if (node >= n) return;
    int base = rowptr[node];
    int deg = rowptr[node + 1] - base;
    int head = lane >> 3;
    float edv = ed[node * 8 + head];

    float acc0 = 0.f, acc1 = 0.f, lsum = 0.f;
    for (int j0 = 0; j0 < deg; j0 += 4) {
        int sa = adj[base + j0];
        int sb = adj[base + j0 + 1];   // padded adj: overread safe, masked below
        int sc = adj[base + j0 + 2];
        int sd = adj[base + j0 + 3];
        float va = es[sa * 8 + head] + edv;
        float vb = es[sb * 8 + head] + edv;
        float vc = es[sc * 8 + head] + edv;
        float vd = es[sd * 8 + head] + edv;
        unsigned int ha = hb[sa * 64 + lane];
        unsigned int hbv = hb[sb * 64 + lane];
        unsigned int hc = hb[sc * 64 + lane];
        unsigned int hd = hb[sd * 64 + lane];
        va = va > 0.f ? va : 0.2f * va;
        vb = vb > 0.f ? vb : 0.2f * vb;
        vc = vc > 0.f ? vc : 0.2f * vc;
        vd = vd > 0.f ? vd : 0.2f * vd;
        float pa = __expf(va);                           // bounded scores: no overflow
        float pb = (j0 + 1 < deg) ? __expf(vb) : 0.f;
        float pc = (j0 + 2 < deg) ? __expf(vc) : 0.f;
        float pd = (j0 + 3 < deg) ? __expf(vd) : 0.f;
        lsum += (pa + pb) + (pc + pd);
        acc0 += pa * bflo2f(ha) + pb * bflo2f(hbv) + pc * bflo2f(hc) + pd * bflo2f(hd);
        acc1 += pa * bfhi2f(ha) + pb * bfhi2f(hbv) + pc * bfhi2f(hc) + pd * bfhi2f(hd);
    }

    float inv = 1.f / (lsum + 1e-16f);
    int ch = lane << 1;
    float o0 = acc0 * inv + ldf(bias, b_off + ch, isf32);
    float o1 = acc1 * inv + ldf(bias, b_off + ch + 1, isf32);
    o0 = o0 > 0.f ? o0 : (__expf(o0) - 1.f);
    o1 = o1 > 0.f ? o1 : (__expf(o1) - 1.f);
    *(float2*)(out + (size_t)node * GAT_F + ch) = make_float2(o0, o1);
}

// ---------- final FC ----------
__global__ __launch_bounds__(256) void k_fc(
    const float* __restrict__ h, const void* __restrict__ fw,
    const void* __restrict__ fb, void* __restrict__ out, int n,
    const int* __restrict__ flags)
{
    __shared__ float fws[GAT_F * GAT_C];
    int isf32 = flags[0];
    int t = threadIdx.x;
    for (int i = t; i < GAT_F * GAT_C; i += 256)
        fws[i] = ldf(fw, i, isf32);
    __syncthreads();
    int row = blockIdx.x * 256 + t;
    if (row >= n) return;
    float acc[16];
    #pragma unroll
    for (int c = 0; c < 16; c++) acc[c] = ldf(fb, c, isf32);
    const float4* hr = (const float4*)(h + (size_t)row * GAT_F);
    for (int k4 = 0; k4 < GAT_F / 4; k4++) {
        float4 xv = hr[k4];
        float xs4[4] = {xv.x, xv.y, xv.z, xv.w};
        #pragma unroll
        for (int kk = 0; kk < 4; kk++) {
            int k = k4 * 4 + kk;
            const float4* wr = (const float4*)(fws + k * GAT_C);
            #pragma unroll
            for (int c4 = 0; c4 < 4; c4++) {
                float4 wv = wr[c4];
                acc[c4 * 4 + 0] += xs4[kk] * wv.x;
                acc[c4 * 4 + 1] += xs4[kk] * wv.y;
                acc[c4 * 4 + 2] += xs4[kk] * wv.z;
                acc[c4 * 4 + 3] += xs4[kk] * wv.w;
            }
        }
    }
    if (isf32) {
        float* o = (float*)out + (size_t)row * GAT_C;
        #pragma unroll
        for (int c = 0; c < 16; c++) o[c] = acc[c];
    } else {
        __hip_bfloat16* o = (__hip_bfloat16*)out + (size_t)row * GAT_C;
        #pragma unroll
        for (int c = 0; c < 16; c++) o[c] = __float2bfloat16(acc[c]);
    }
}

extern "C" void kernel_launch(void* const* d_in, const int* in_sizes, int n_in,
                              void* d_out, int out_size, void* d_ws, size_t ws_size,
                              hipStream_t stream) {
    const void* x      = d_in[0];
    const void* Ws     = d_in[1];
    const void* att_s  = d_in[2];
    const void* att_d  = d_in[3];
    const void* biases = d_in[4];
    const void* fc_w   = d_in[5];
    const void* fc_b   = d_in[6];
    const int*  ei     = (const int*)d_in[7];

    const int N  = in_sizes[0] / GAT_F;
    const int E  = in_sizes[7] / 2;
    const int L  = in_sizes[1] / (GAT_F * GAT_F);
    const int ET = E + N;

    char* w = (char*)d_ws;
    int* flags        = (int*)w;          w += 64;
    float* hA         = (float*)w;        w += (size_t)N * GAT_F * 4;   // fp32 agg out / next input
    unsigned int* hB  = (unsigned int*)w; w += (size_t)N * 64 * 4;      // packed bf16 gemm out
    float* es         = (float*)w;        w += (size_t)N * GAT_H * 4;
    float* ed         = (float*)w;        w += (size_t)N * GAT_H * 4;
    int* rowptr       = (int*)w;          w += (((size_t)(N + 1) * 4 + 15) & ~15ull);
    int* cursor       = (int*)w;          w += (size_t)N * 4;           // degree, then cursor
    int* bsum         = (int*)w;          w += 1024 * 4;                // block sums for scan
    int* adj          = (int*)w;          w += (size_t)(ET + 16) * 4;

    int nb_n = (N + 255) / 256;
    int nb_e = (E + 255) / 256;
    int nb_s = (N + 1023) / 1024;   // scan blocks (1024 elems each)

    k_detect<<<1, 256, 0, stream>>>((const unsigned short*)x, ei, flags);

    k_init_deg<<<nb_n, 256, 0, stream>>>(cursor, N);
    k_count_deg<<<nb_e, 256, 0, stream>>>(ei, cursor, E, flags);
    k_scan_blk<<<nb_s, 256, 0, stream>>>(cursor, rowptr, bsum, N);
    k_scan_top<<<1, 256, 0, stream>>>(bsum, rowptr, nb_s, N);
    k_place_add<<<nb_n, 256, 0, stream>>>(rowptr, bsum, adj, cursor, N);
    k_scatter<<<nb_e, 256, 0, stream>>>(ei, rowptr, cursor, adj, E, flags);

    int nb_g = (N + 31) / 32;
    int nb_a = (N + 3) / 4;
    for (int l = 0; l < L; l++) {
        k_gemm_scores<<<nb_g, 256, 0, stream>>>(
            (l == 0) ? x : (const void*)hA, (l == 0) ? 1 : 0,
            Ws, (long)l * GAT_F * GAT_F,
            att_s, att_d, (long)l * GAT_H * GAT_C,
            hB, es, ed, N, flags);
        k_aggregate<<<nb_a, 256, 0, stream>>>(
            hB, es, ed, rowptr, adj,
            biases, (long)l * GAT_F, hA, N, flags);
    }
    k_fc<<<nb_n, 256, 0, stream>>>(hA, fc_w, fc_b, d_out, N, flags);
}

// Round 6
// 409.015 us; speedup vs baseline: 1.6784x; 1.1230x over previous
//
#include <hip/hip_runtime.h>
#include <hip/hip_bf16.h>

// GAT: N=50000 nodes, E=800000 edges, L=3 layers, H=8 heads, C=16, F=128.
// flags[0]=1 -> float tensors fp32 (else bf16); flags[1]=1 -> edge_index int64.
// R6: GEMM rewritten with v_mfma_f32_16x16x32_bf16. W pre-transposed+bf16-packed
// once per call (k_prep), attention scores folded in as 16 extra B columns
// (Wa = W @ A'), so es/ed fall out of the MFMA C-layout with plain stores.

#define GAT_F 128
#define GAT_H 8
#define GAT_C 16

typedef __attribute__((ext_vector_type(8))) short bf16x8;
typedef __attribute__((ext_vector_type(4))) float f32x4;

__device__ __forceinline__ float bf2f(unsigned short u) {
    union { unsigned int i; float f; } x; x.i = ((unsigned int)u) << 16; return x.f;
}
__device__ __forceinline__ float bfhi2f(unsigned int u) {
    union { unsigned int i; float f; } x; x.i = u & 0xFFFF0000u; return x.f;
}
__device__ __forceinline__ float bflo2f(unsigned int u) {
    union { unsigned int i; float f; } x; x.i = u << 16; return x.f;
}
__device__ __forceinline__ unsigned int pk_bf16(float a, float b) {  // rne pack
    union { float f; unsigned int i; } ua, ub;
    ua.f = a; ub.f = b;
    unsigned int ra = (ua.i + 0x7FFFu + ((ua.i >> 16) & 1u)) >> 16;
    unsigned int rb = (ub.i + 0x7FFFu + ((ub.i >> 16) & 1u)) & 0xFFFF0000u;
    return ra | rb;
}
__device__ __forceinline__ unsigned short f2bf(float a) {
    union { float f; unsigned int i; } ua; ua.f = a;
    return (unsigned short)((ua.i + 0x7FFFu + ((ua.i >> 16) & 1u)) >> 16);
}
__device__ __forceinline__ float ldf(const void* p, size_t i, int isf32) {
    return isf32 ? ((const float*)p)[i] : bf2f(((const unsigned short*)p)[i]);
}
__device__ __forceinline__ int ldei(const int* ei, int i, int is64) {
    return is64 ? ei[2 * (size_t)i] : ei[i];
}

// ---------- dtype detection ----------
__global__ void k_detect(const unsigned short* __restrict__ xb,
                         const int* __restrict__ ei, int* flags) {
    __shared__ int nan_cnt, zero_cnt;
    if (threadIdx.x == 0) { nan_cnt = 0; zero_cnt = 0; }
    __syncthreads();
    int t = threadIdx.x;
    int ln = 0;
    for (int i = t; i < 8192; i += 256) {
        unsigned short u = xb[i];
        if ((u & 0x7F80) == 0x7F80) ln++;   // bf16 inf/nan pattern
    }
    int lz = 0;
    for (int i = t; i < 2048; i += 256) {
        if (ei[2 * i + 1] == 0) lz++;       // int64 high words all zero
    }
    if (ln) atomicAdd(&nan_cnt, ln);
    if (lz) atomicAdd(&zero_cnt, lz);
    __syncthreads();
    if (t == 0) {
        flags[0] = (nan_cnt > 3) ? 1 : 0;
        flags[1] = (zero_cnt > 1024) ? 1 : 0;
    }
}

// ---------- prep: W -> bf16 transposed (wt[l][c][k]) and Wa = W@A' (wa[l][j][k]) ----------
__global__ void k_prep(const void* __restrict__ W, const void* __restrict__ asrc,
                       const void* __restrict__ adst,
                       unsigned short* __restrict__ wt, unsigned short* __restrict__ wa,
                       int Lw, const int* __restrict__ flags) {
    int isf32 = flags[0];
    int b = blockIdx.x, t = threadIdx.x;
    if (b < Lw * 64) {
        int gid = b * 256 + t;                 // over L*16384
        int l = gid >> 14, r = gid & 16383;
        int c = r >> 7, k = r & 127;
        float v = ldf(W, (size_t)l * 16384 + k * 128 + c, isf32);
        wt[gid] = f2bf(v);                     // wt layout: l*16384 + c*128 + k
    } else {
        int id = (b - Lw * 64) * 256 + t;      // over L*2048
        int l = id >> 11, q = id & 2047;
        int j = q >> 7, k = q & 127;
        int head = j & 7;
        const void* av = (j < 8) ? asrc : adst;
        float acc = 0.f;
        #pragma unroll
        for (int cc = 0; cc < 16; cc++) {
            float w = ldf(W, (size_t)l * 16384 + k * 128 + head * 16 + cc, isf32);
            float a = ldf(av, (size_t)l * 128 + head * 16 + cc, isf32);
            acc += w * a;
        }
        wa[id] = f2bf(acc);                    // wa layout: l*2048 + j*128 + k
    }
}

// ---------- CSR build ----------
__global__ void k_init_deg(int* deg, int n) {
    int i = blockIdx.x * 256 + threadIdx.x;
    if (i < n) deg[i] = 1;  // self loop
}

__global__ void k_count_deg(const int* __restrict__ ei, int* deg, int E,
                            const int* __restrict__ flags) {
    int k = blockIdx.x * 256 + threadIdx.x;
    int is64 = flags[1];
    if (k < E) atomicAdd(&deg[ldei(ei, E + k, is64)], 1);
}

__global__ __launch_bounds__(256) void k_scan_blk(
    const int* __restrict__ deg, int* __restrict__ rp_local,
    int* __restrict__ bsum, int n)
{
    int b = blockIdx.x, t = threadIdx.x;
    int i0 = b * 1024 + t * 4;
    int v0 = 0, v1 = 0, v2 = 0, v3 = 0;
    if (i0 + 3 < n) {
        int4 d = *(const int4*)(deg + i0);
        v0 = d.x; v1 = d.y; v2 = d.z; v3 = d.w;
    } else {
        if (i0     < n) v0 = deg[i0];
        if (i0 + 1 < n) v1 = deg[i0 + 1];
        if (i0 + 2 < n) v2 = deg[i0 + 2];
        if (i0 + 3 < n) v3 = deg[i0 + 3];
    }
    int s = v0 + v1 + v2 + v3;
    int lane = t & 63, wid = t >> 6;
    int sc = s;
    #pragma unroll
    for (int off = 1; off < 64; off <<= 1) {
        int o = __shfl_up(sc, off);
        if (lane >= off) sc += o;
    }
    __shared__ int wsum[4];
    if (lane == 63) wsum[wid] = sc;
    __syncthreads();
    int woff = 0;
    #pragma unroll
    for (int w2 = 0; w2 < 4; w2++) if (w2 < wid) woff += wsum[w2];
    int excl = woff + sc - s;
    if (i0     < n) rp_local[i0]     = excl;
    if (i0 + 1 < n) rp_local[i0 + 1] = excl + v0;
    if (i0 + 2 < n) rp_local[i0 + 2] = excl + v0 + v1;
    if (i0 + 3 < n) rp_local[i0 + 3] = excl + v0 + v1 + v2;
    if (t == 255) bsum[b] = woff + sc;
}

__global__ __launch_bounds__(256) void k_scan_top(
    int* __restrict__ bsum, int* __restrict__ rowptr, int nb, int n)
{
    __shared__ int sh[1024];
    int t = threadIdx.x;
    for (int i = t; i < 1024; i += 256) sh[i] = (i < nb) ? bsum[i] : 0;
    __syncthreads();
    for (int off = 1; off < 1024; off <<= 1) {
        int vals[4];
        #pragma unroll
        for (int k = 0; k < 4; k++) {
            int i = t + 256 * k;
            vals[k] = (i >= off) ? sh[i - off] : 0;
        }
        __syncthreads();
        #pragma unroll
        for (int k = 0; k < 4; k++) sh[t + 256 * k] += vals[k];
        __syncthreads();
    }
    for (int i = t; i < nb; i += 256) bsum[i] = (i == 0) ? 0 : sh[i - 1];
    if (t == 0) rowptr[n] = sh[nb - 1];
}

__global__ void k_place_add(int* __restrict__ rowptr, const int* __restrict__ bsum,
                            int* __restrict__ adj, int* __restrict__ cursor, int n)
{
    int i = blockIdx.x * 256 + threadIdx.x;
    if (i < n) {
        int r = rowptr[i] + bsum[i >> 10];
        rowptr[i] = r;
        adj[r] = i;
        cursor[i] = 1;
    }
    if (blockIdx.x == 0 && threadIdx.x < 8) adj[rowptr[n] + threadIdx.x] = 0;
}

__global__ void k_scatter(const int* __restrict__ ei, const int* __restrict__ rowptr,
                          int* __restrict__ cursor, int* __restrict__ adj, int E,
                          const int* __restrict__ flags) {
    int k = blockIdx.x * 256 + threadIdx.x;
    int is64 = flags[1];
    if (k < E) {
        int s = ldei(ei, k, is64);
        int d = ldei(ei, E + k, is64);
        int p = atomicAdd(&cursor[d], 1);
        adj[rowptr[d] + p] = s;
    }
}

// ---------- MFMA GEMM: h(+scores) = x @ [Wt | Wa] ----------
// Block: 256 thr (4 waves), 64 rows. LDS: xl 64x136 bf16, wl 144x136 bf16.
// Wave w computes rows w*16..+15, all 144 cols (9 tiles of 16; tile 8 = scores).
__global__ __launch_bounds__(256) void k_gemm_mfma(
    const void* __restrict__ xin, int x_is_input,
    const unsigned short* __restrict__ wt,   // [c][k] bf16, this layer
    const unsigned short* __restrict__ wa,   // [j][k] bf16, this layer
    unsigned int* __restrict__ hb, float* __restrict__ es, float* __restrict__ ed,
    int n, const int* __restrict__ flags)
{
    __shared__ unsigned short xl[64 * 136];
    __shared__ unsigned short wl[144 * 136];
    int isf32 = flags[0];
    int t = threadIdx.x;
    int row0 = blockIdx.x * 64;

    // stage x tile (convert to bf16)
    if (isf32 || !x_is_input) {
        const float4* xg = (const float4*)xin;
        for (int i = t; i < 2048; i += 256) {
            int r = i >> 5, c4 = i & 31;
            int gr = row0 + r;
            uint2 u = make_uint2(0u, 0u);
            if (gr < n) {
                float4 v = xg[(size_t)gr * 32 + c4];
                u = make_uint2(pk_bf16(v.x, v.y), pk_bf16(v.z, v.w));
            }
            *(uint2*)&xl[r * 136 + c4 * 4] = u;
        }
    } else {
        const ushort4* xg = (const ushort4*)xin;
        for (int i = t; i < 2048; i += 256) {
            int r = i >> 5, c4 = i & 31;
            int gr = row0 + r;
            ushort4 v = make_ushort4(0, 0, 0, 0);
            if (gr < n) v = xg[(size_t)gr * 32 + c4];
            *(ushort4*)&xl[r * 136 + c4 * 4] = v;
        }
    }
    // stage W^T (cols 0..127) and Wa (cols 128..143)
    {
        const ushort4* wg = (const ushort4*)wt;
        for (int i = t; i < 4096; i += 256) {
            int c = i >> 5, k4 = i & 31;
            *(ushort4*)&wl[c * 136 + k4 * 4] = wg[i];
        }
        const ushort4* wag = (const ushort4*)wa;
        for (int i = t; i < 512; i += 256) {
            int j = i >> 5, k4 = i & 31;
            *(ushort4*)&wl[(128 + j) * 136 + k4 * 4] = wag[i];
        }
    }
    __syncthreads();

    int lane = t & 63, wid = t >> 6, quad = lane >> 4, col = lane & 15;
    f32x4 acc[9];
    #pragma unroll
    for (int ct = 0; ct < 9; ct++) acc[ct] = (f32x4){0.f, 0.f, 0.f, 0.f};

    #pragma unroll
    for (int ks = 0; ks < 4; ks++) {
        int k0 = ks * 32;
        bf16x8 af = *(const bf16x8*)&xl[(wid * 16 + col) * 136 + k0 + quad * 8];
        #pragma unroll
        for (int ct = 0; ct < 9; ct++) {
            bf16x8 bf = *(const bf16x8*)&wl[(ct * 16 + col) * 136 + k0 + quad * 8];
            acc[ct] = __builtin_amdgcn_mfma_f32_16x16x32_bf16(af, bf, acc[ct], 0, 0, 0);
        }
    }

    // epilogue: h tiles (pack bf16 pairs via lane-xor shuffle)
    #pragma unroll
    for (int ct = 0; ct < 8; ct++) {
        #pragma unroll
        for (int r = 0; r < 4; r++) {
            int grow = row0 + wid * 16 + quad * 4 + r;
            float v = acc[ct][r];
            float vp = __shfl_xor(v, 1);
            if (!(lane & 1) && grow < n)
                hb[(size_t)grow * 64 + ct * 8 + (col >> 1)] = pk_bf16(v, vp);
        }
    }
    // scores tile: cols 0-7 = e_src heads, 8-15 = e_dst heads
    #pragma unroll
    for (int r = 0; r < 4; r++) {
        int grow = row0 + wid * 16 + quad * 4 + r;
        float v = acc[8][r];
        if (grow < n) {
            if (col < 8) es[(size_t)grow * 8 + col] = v;
            else         ed[(size_t)grow * 8 + col - 8] = v;
        }
    }
}

// ---------- aggregation: one wave per node, single pass, no max-shift ----------
__global__ __launch_bounds__(256) void k_aggregate(
    const unsigned int* __restrict__ hb,   // packed bf16x2, stride 64 dwords
    const float* __restrict__ es, const float* __restrict__ ed,
    const int* __restrict__ rowptr, const int* __restrict__ adj,
    const void* __restrict__ bias, long b_off, float* __restrict__ out, int n,
    const int* __restrict__ flags)
{
    int isf32 = flags[0];
    int lane = threadIdx.x & 63;
    int node = blockIdx.x * 4 + (threadIdx.x >> 6);
    if (node >= n) return;
    int base = rowptr[node];
    int deg = rowptr[node + 1] - base;
    int head = lane >> 3;
    float edv = ed[node * 8 + head];

    float acc0 = 0.f, acc1 = 0.f, lsum = 0.f;
    for (int j0 = 0; j0 < deg; j0 += 4) {
        int sa = adj[base + j0];
        int sb = adj[base + j0 + 1];
        int sc = adj[base + j0 + 2];
        int sd = adj[base + j0 + 3];
        float va = es[sa * 8 + head] + edv;
        float vb = es[sb * 8 + head] + edv;
        float vc = es[sc * 8 + head] + edv;
        float vd = es[sd * 8 + head] + edv;
        unsigned int ha = hb[sa * 64 + lane];
        unsigned int hbv = hb[sb * 64 + lane];
        unsigned int hc = hb[sc * 64 + lane];
        unsigned int hd = hb[sd * 64 + lane];
        va = va > 0.f ? va : 0.2f * va;
        vb = vb > 0.f ? vb : 0.2f * vb;
        vc = vc > 0.f ? vc : 0.2f * vc;
        vd = vd > 0.f ? vd : 0.2f * vd;
        float pa = __expf(va);
        float pb = (j0 + 1 < deg) ? __expf(vb) : 0.f;
        float pc = (j0 + 2 < deg) ? __expf(vc) : 0.f;
        float pd = (j0 + 3 < deg) ? __expf(vd) : 0.f;
        lsum += (pa + pb) + (pc + pd);
        acc0 += pa * bflo2f(ha) + pb * bflo2f(hbv) + pc * bflo2f(hc) + pd * bflo2f(hd);
        acc1 += pa * bfhi2f(ha) + pb * bfhi2f(hbv) + pc * bfhi2f(hc) + pd * bfhi2f(hd);
    }

    float inv = 1.f / (lsum + 1e-16f);
    int ch = lane << 1;
    float o0 = acc0 * inv + ldf(bias, b_off + ch, isf32);
    float o1 = acc1 * inv + ldf(bias, b_off + ch + 1, isf32);
    o0 = o0 > 0.f ? o0 : (__expf(o0) - 1.f);
    o1 = o1 > 0.f ? o1 : (__expf(o1) - 1.f);
    *(float2*)(out + (size_t)node * GAT_F + ch) = make_float2(o0, o1);
}

// ---------- final FC ----------
__global__ __launch_bounds__(256) void k_fc(
    const float* __restrict__ h, const void* __restrict__ fw,
    const void* __restrict__ fb, void* __restrict__ out, int n,
    const int* __restrict__ flags)
{
    __shared__ float fws[GAT_F * GAT_C];
    int isf32 = flags[0];
    int t = threadIdx.x;
    for (int i = t; i < GAT_F * GAT_C; i += 256)
        fws[i] = ldf(fw, i, isf32);
    __syncthreads();
    int row = blockIdx.x * 256 + t;
    if (row >= n) return;
    float acc[16];
    #pragma unroll
    for (int c = 0; c < 16; c++) acc[c] = ldf(fb, c, isf32);
    const float4* hr = (const float4*)(h + (size_t)row * GAT_F);
    for (int k4 = 0; k4 < GAT_F / 4; k4++) {
        float4 xv = hr[k4];
        float xs4[4] = {xv.x, xv.y, xv.z, xv.w};
        #pragma unroll
        for (int kk = 0; kk < 4; kk++) {
            int k = k4 * 4 + kk;
            const float4* wr = (const float4*)(fws + k * GAT_C);
            #pragma unroll
            for (int c4 = 0; c4 < 4; c4++) {
                float4 wv = wr[c4];
                acc[c4 * 4 + 0] += xs4[kk] * wv.x;
                acc[c4 * 4 + 1] += xs4[kk] * wv.y;
                acc[c4 * 4 + 2] += xs4[kk] * wv.z;
                acc[c4 * 4 + 3] += xs4[kk] * wv.w;
            }
        }
    }
    if (isf32) {
        float* o = (float*)out + (size_t)row * GAT_C;
        #pragma unroll
        for (int c = 0; c < 16; c++) o[c] = acc[c];
    } else {
        __hip_bfloat16* o = (__hip_bfloat16*)out + (size_t)row * GAT_C;
        #pragma unroll
        for (int c = 0; c < 16; c++) o[c] = __float2bfloat16(acc[c]);
    }
}

extern "C" void kernel_launch(void* const* d_in, const int* in_sizes, int n_in,
                              void* d_out, int out_size, void* d_ws, size_t ws_size,
                              hipStream_t stream) {
    const void* x      = d_in[0];
    const void* Ws     = d_in[1];
    const void* att_s  = d_in[2];
    const void* att_d  = d_in[3];
    const void* biases = d_in[4];
    const void* fc_w   = d_in[5];
    const void* fc_b   = d_in[6];
    const int*  ei     = (const int*)d_in[7];

    const int N  = in_sizes[0] / GAT_F;
    const int E  = in_sizes[7] / 2;
    const int L  = in_sizes[1] / (GAT_F * GAT_F);
    const int ET = E + N;

    char* w = (char*)d_ws;
    int* flags         = (int*)w;            w += 64;
    float* hA          = (float*)w;          w += (size_t)N * GAT_F * 4;
    unsigned int* hB   = (unsigned int*)w;   w += (size_t)N * 64 * 4;
    float* es          = (float*)w;          w += (size_t)N * GAT_H * 4;
    float* ed          = (float*)w;          w += (size_t)N * GAT_H * 4;
    int* rowptr        = (int*)w;            w += (((size_t)(N + 1) * 4 + 15) & ~15ull);
    int* cursor        = (int*)w;            w += (size_t)N * 4;
    int* bsum          = (int*)w;            w += 1024 * 4;
    int* adj           = (int*)w;            w += (size_t)(ET + 16) * 4;
    unsigned short* wt = (unsigned short*)w; w += (size_t)L * 16384 * 2;
    unsigned short* wa = (unsigned short*)w; w += (size_t)L * 2048 * 2;

    int nb_n = (N + 255) / 256;
    int nb_e = (E + 255) / 256;
    int nb_s = (N + 1023) / 1024;

    k_detect<<<1, 256, 0, stream>>>((const unsigned short*)x, ei, flags);
    k_prep<<<L * 64 + L * 8, 256, 0, stream>>>(Ws, att_s, att_d, wt, wa, L, flags);

    k_init_deg<<<nb_n, 256, 0, stream>>>(cursor, N);
    k_count_deg<<<nb_e, 256, 0, stream>>>(ei, cursor, E, flags);
    k_scan_blk<<<nb_s, 256, 0, stream>>>(cursor, rowptr, bsum, N);
    k_scan_top<<<1, 256, 0, stream>>>(bsum, rowptr, nb_s, N);
    k_place_add<<<nb_n, 256, 0, stream>>>(rowptr, bsum, adj, cursor, N);
    k_scatter<<<nb_e, 256, 0, stream>>>(ei, rowptr, cursor, adj, E, flags);

    int nb_g = (N + 63) / 64;
    int nb_a = (N + 3) / 4;
    for (int l = 0; l < L; l++) {
        k_gemm_mfma<<<nb_g, 256, 0, stream>>>(
            (l == 0) ? x : (const void*)hA, (l == 0) ? 1 : 0,
            wt + (size_t)l * 16384, wa + (size_t)l * 2048,
            hB, es, ed, N, flags);
        k_aggregate<<<nb_a, 256, 0, stream>>>(
            hB, es, ed, rowptr, adj,
            biases, (long)l * GAT_F, hA, N, flags);
    }
    k_fc<<<nb_n, 256, 0, stream>>>(hA, fc_w, fc_b, d_out, N, flags);
}

// Round 7
// 400.595 us; speedup vs baseline: 1.7137x; 1.0210x over previous
//
#include <hip/hip_runtime.h>
#include <hip/hip_bf16.h>

// GAT: N=50000 nodes, E=800000 edges, L=3 layers, H=8 heads, C=16, F=128.
// flags[0]=1 -> float tensors fp32 (else bf16); flags[1]=1 -> edge_index int64.
// R7: two-phase aggregate. Phase 1 (lane=edge): compute all 8 head-alphas per
// edge once (8 exps per 64 edges, not 1 per edge wave-wide), stash alpha+src in
// per-wave LDS. Phase 2 (lane=channel): ds_read alphas (broadcast), gather h,
// FMA; denominator = sum of alphas accumulated in-loop (no cross-lane reduce).

#define GAT_F 128
#define GAT_H 8
#define GAT_C 16

typedef __attribute__((ext_vector_type(8))) short bf16x8;
typedef __attribute__((ext_vector_type(4))) float f32x4;

__device__ __forceinline__ float bf2f(unsigned short u) {
    union { unsigned int i; float f; } x; x.i = ((unsigned int)u) << 16; return x.f;
}
__device__ __forceinline__ float bfhi2f(unsigned int u) {
    union { unsigned int i; float f; } x; x.i = u & 0xFFFF0000u; return x.f;
}
__device__ __forceinline__ float bflo2f(unsigned int u) {
    union { unsigned int i; float f; } x; x.i = u << 16; return x.f;
}
__device__ __forceinline__ unsigned int pk_bf16(float a, float b) {  // rne pack
    union { float f; unsigned int i; } ua, ub;
    ua.f = a; ub.f = b;
    unsigned int ra = (ua.i + 0x7FFFu + ((ua.i >> 16) & 1u)) >> 16;
    unsigned int rb = (ub.i + 0x7FFFu + ((ub.i >> 16) & 1u)) & 0xFFFF0000u;
    return ra | rb;
}
__device__ __forceinline__ unsigned short f2bf(float a) {
    union { float f; unsigned int i; } ua; ua.f = a;
    return (unsigned short)((ua.i + 0x7FFFu + ((ua.i >> 16) & 1u)) >> 16);
}
__device__ __forceinline__ float ldf(const void* p, size_t i, int isf32) {
    return isf32 ? ((const float*)p)[i] : bf2f(((const unsigned short*)p)[i]);
}
__device__ __forceinline__ int ldei(const int* ei, int i, int is64) {
    return is64 ? ei[2 * (size_t)i] : ei[i];
}

// ---------- dtype detection ----------
__global__ void k_detect(const unsigned short* __restrict__ xb,
                         const int* __restrict__ ei, int* flags) {
    __shared__ int nan_cnt, zero_cnt;
    if (threadIdx.x == 0) { nan_cnt = 0; zero_cnt = 0; }
    __syncthreads();
    int t = threadIdx.x;
    int ln = 0;
    for (int i = t; i < 8192; i += 256) {
        unsigned short u = xb[i];
        if ((u & 0x7F80) == 0x7F80) ln++;   // bf16 inf/nan pattern
    }
    int lz = 0;
    for (int i = t; i < 2048; i += 256) {
        if (ei[2 * i + 1] == 0) lz++;       // int64 high words all zero
    }
    if (ln) atomicAdd(&nan_cnt, ln);
    if (lz) atomicAdd(&zero_cnt, lz);
    __syncthreads();
    if (t == 0) {
        flags[0] = (nan_cnt > 3) ? 1 : 0;
        flags[1] = (zero_cnt > 1024) ? 1 : 0;
    }
}

// ---------- prep: W -> bf16 transposed (wt[l][c][k]) and Wa = W@A' (wa[l][j][k]) ----------
__global__ void k_prep(const void* __restrict__ W, const void* __restrict__ asrc,
                       const void* __restrict__ adst,
                       unsigned short* __restrict__ wt, unsigned short* __restrict__ wa,
                       int Lw, const int* __restrict__ flags) {
    int isf32 = flags[0];
    int b = blockIdx.x, t = threadIdx.x;
    if (b < Lw * 64) {
        int gid = b * 256 + t;                 // over L*16384
        int l = gid >> 14, r = gid & 16383;
        int c = r >> 7, k = r & 127;
        float v = ldf(W, (size_t)l * 16384 + k * 128 + c, isf32);
        wt[gid] = f2bf(v);                     // wt layout: l*16384 + c*128 + k
    } else {
        int id = (b - Lw * 64) * 256 + t;      // over L*2048
        int l = id >> 11, q = id & 2047;
        int j = q >> 7, k = q & 127;
        int head = j & 7;
        const void* av = (j < 8) ? asrc : adst;
        float acc = 0.f;
        #pragma unroll
        for (int cc = 0; cc < 16; cc++) {
            float w = ldf(W, (size_t)l * 16384 + k * 128 + head * 16 + cc, isf32);
            float a = ldf(av, (size_t)l * 128 + head * 16 + cc, isf32);
            acc += w * a;
        }
        wa[id] = f2bf(acc);                    // wa layout: l*2048 + j*128 + k
    }
}

// ---------- CSR build ----------
__global__ void k_init_deg(int* deg, int n) {
    int i = blockIdx.x * 256 + threadIdx.x;
    if (i < n) deg[i] = 1;  // self loop
}

__global__ void k_count_deg(const int* __restrict__ ei, int* deg, int E,
                            const int* __restrict__ flags) {
    int k = blockIdx.x * 256 + threadIdx.x;
    int is64 = flags[1];
    if (k < E) atomicAdd(&deg[ldei(ei, E + k, is64)], 1);
}

__global__ __launch_bounds__(256) void k_scan_blk(
    const int* __restrict__ deg, int* __restrict__ rp_local,
    int* __restrict__ bsum, int n)
{
    int b = blockIdx.x, t = threadIdx.x;
    int i0 = b * 1024 + t * 4;
    int v0 = 0, v1 = 0, v2 = 0, v3 = 0;
    if (i0 + 3 < n) {
        int4 d = *(const int4*)(deg + i0);
        v0 = d.x; v1 = d.y; v2 = d.z; v3 = d.w;
    } else {
        if (i0     < n) v0 = deg[i0];
        if (i0 + 1 < n) v1 = deg[i0 + 1];
        if (i0 + 2 < n) v2 = deg[i0 + 2];
        if (i0 + 3 < n) v3 = deg[i0 + 3];
    }
    int s = v0 + v1 + v2 + v3;
    int lane = t & 63, wid = t >> 6;
    int sc = s;
    #pragma unroll
    for (int off = 1; off < 64; off <<= 1) {
        int o = __shfl_up(sc, off);
        if (lane >= off) sc += o;
    }
    __shared__ int wsum[4];
    if (lane == 63) wsum[wid] = sc;
    __syncthreads();
    int woff = 0;
    #pragma unroll
    for (int w2 = 0; w2 < 4; w2++) if (w2 < wid) woff += wsum[w2];
    int excl = woff + sc - s;
    if (i0     < n) rp_local[i0]     = excl;
    if (i0 + 1 < n) rp_local[i0 + 1] = excl + v0;
    if (i0 + 2 < n) rp_local[i0 + 2] = excl + v0 + v1;
    if (i0 + 3 < n) rp_local[i0 + 3] = excl + v0 + v1 + v2;
    if (t == 255) bsum[b] = woff + sc;
}

__global__ __launch_bounds__(256) void k_scan_top(
    int* __restrict__ bsum, int* __restrict__ rowptr, int nb, int n)
{
    __shared__ int sh[1024];
    int t = threadIdx.x;
    for (int i = t; i < 1024; i += 256) sh[i] = (i < nb) ? bsum[i] : 0;
    __syncthreads();
    for (int off = 1; off < 1024; off <<= 1) {
        int vals[4];
        #pragma unroll
        for (int k = 0; k < 4; k++) {
            int i = t + 256 * k;
            vals[k] = (i >= off) ? sh[i - off] : 0;
        }
        __syncthreads();
        #pragma unroll
        for (int k = 0; k < 4; k++) sh[t + 256 * k] += vals[k];
        __syncthreads();
    }
    for (int i = t; i < nb; i += 256) bsum[i] = (i == 0) ? 0 : sh[i - 1];
    if (t == 0) rowptr[n] = sh[nb - 1];
}

__global__ void k_place_add(int* __restrict__ rowptr, const int* __restrict__ bsum,
                            int* __restrict__ adj, int* __restrict__ cursor, int n)
{
    int i = blockIdx.x * 256 + threadIdx.x;
    if (i < n) {
        int r = rowptr[i] + bsum[i >> 10];
        rowptr[i] = r;
        adj[r] = i;
        cursor[i] = 1;
    }
    if (blockIdx.x == 0 && threadIdx.x < 8) adj[rowptr[n] + threadIdx.x] = 0;
}

__global__ void k_scatter(const int* __restrict__ ei, const int* __restrict__ rowptr,
                          int* __restrict__ cursor, int* __restrict__ adj, int E,
                          const int* __restrict__ flags) {
    int k = blockIdx.x * 256 + threadIdx.x;
    int is64 = flags[1];
    if (k < E) {
        int s = ldei(ei, k, is64);
        int d = ldei(ei, E + k, is64);
        int p = atomicAdd(&cursor[d], 1);
        adj[rowptr[d] + p] = s;
    }
}

// ---------- MFMA GEMM: h(+scores) = x @ [Wt | Wa] ----------
__global__ __launch_bounds__(256) void k_gemm_mfma(
    const void* __restrict__ xin, int x_is_input,
    const unsigned short* __restrict__ wt,   // [c][k] bf16, this layer
    const unsigned short* __restrict__ wa,   // [j][k] bf16, this layer
    unsigned int* __restrict__ hb, float* __restrict__ es, float* __restrict__ ed,
    int n, const int* __restrict__ flags)
{
    __shared__ unsigned short xl[64 * 136];
    __shared__ unsigned short wl[144 * 136];
    int isf32 = flags[0];
    int t = threadIdx.x;
    int row0 = blockIdx.x * 64;

    if (isf32 || !x_is_input) {
        const float4* xg = (const float4*)xin;
        for (int i = t; i < 2048; i += 256) {
            int r = i >> 5, c4 = i & 31;
            int gr = row0 + r;
            uint2 u = make_uint2(0u, 0u);
            if (gr < n) {
                float4 v = xg[(size_t)gr * 32 + c4];
                u = make_uint2(pk_bf16(v.x, v.y), pk_bf16(v.z, v.w));
            }
            *(uint2*)&xl[r * 136 + c4 * 4] = u;
        }
    } else {
        const ushort4* xg = (const ushort4*)xin;
        for (int i = t; i < 2048; i += 256) {
            int r = i >> 5, c4 = i & 31;
            int gr = row0 + r;
            ushort4 v = make_ushort4(0, 0, 0, 0);
            if (gr < n) v = xg[(size_t)gr * 32 + c4];
            *(ushort4*)&xl[r * 136 + c4 * 4] = v;
        }
    }
    {
        const ushort4* wg = (const ushort4*)wt;
        for (int i = t; i < 4096; i += 256) {
            int c = i >> 5, k4 = i & 31;
            *(ushort4*)&wl[c * 136 + k4 * 4] = wg[i];
        }
        const ushort4* wag = (const ushort4*)wa;
        for (int i = t; i < 512; i += 256) {
            int j = i >> 5, k4 = i & 31;
            *(ushort4*)&wl[(128 + j) * 136 + k4 * 4] = wag[i];
        }
    }
    __syncthreads();

    int lane = t & 63, wid = t >> 6, quad = lane >> 4, col = lane & 15;
    f32x4 acc[9];
    #pragma unroll
    for (int ct = 0; ct < 9; ct++) acc[ct] = (f32x4){0.f, 0.f, 0.f, 0.f};

    #pragma unroll
    for (int ks = 0; ks < 4; ks++) {
        int k0 = ks * 32;
        bf16x8 af = *(const bf16x8*)&xl[(wid * 16 + col) * 136 + k0 + quad * 8];
        #pragma unroll
        for (int ct = 0; ct < 9; ct++) {
            bf16x8 bf = *(const bf16x8*)&wl[(ct * 16 + col) * 136 + k0 + quad * 8];
            acc[ct] = __builtin_amdgcn_mfma_f32_16x16x32_bf16(af, bf, acc[ct], 0, 0, 0);
        }
    }

    #pragma unroll
    for (int ct = 0; ct < 8; ct++) {
        #pragma unroll
        for (int r = 0; r < 4; r++) {
            int grow = row0 + wid * 16 + quad * 4 + r;
            float v = acc[ct][r];
            float vp = __shfl_xor(v, 1);
            if (!(lane & 1) && grow < n)
                hb[(size_t)grow * 64 + ct * 8 + (col >> 1)] = pk_bf16(v, vp);
        }
    }
    #pragma unroll
    for (int r = 0; r < 4; r++) {
        int grow = row0 + wid * 16 + quad * 4 + r;
        float v = acc[8][r];
        if (grow < n) {
            if (col < 8) es[(size_t)grow * 8 + col] = v;
            else         ed[(size_t)grow * 8 + col - 8] = v;
        }
    }
}

// ---------- aggregation: one wave per node, two-phase LDS-alpha ----------
__global__ __launch_bounds__(256) void k_aggregate(
    const unsigned int* __restrict__ hb,   // packed bf16x2, stride 64 dwords
    const float* __restrict__ es, const float* __restrict__ ed,
    const int* __restrict__ rowptr, const int* __restrict__ adj,
    const void* __restrict__ bias, long b_off, float* __restrict__ out, int n,
    const int* __restrict__ flags)
{
    __shared__ __align__(16) float alds[4][64 * 12];   // per-wave alpha[edge][head], stride 12
    __shared__ __align__(16) int   slds[4][64];        // per-wave src ids
    int isf32 = flags[0];
    int lane = threadIdx.x & 63;
    int wid = threadIdx.x >> 6;
    int node = blockIdx.x * 4 + wid;
    if (node >= n) return;
    int base = rowptr[node];
    int deg = rowptr[node + 1] - base;
    int head = lane >> 3;

    const float4* es4 = (const float4*)es;
    const float4* ed4 = (const float4*)ed;
    float edv[8];
    {
        float4 a = ed4[node * 2];
        float4 b = ed4[node * 2 + 1];
        edv[0] = a.x; edv[1] = a.y; edv[2] = a.z; edv[3] = a.w;
        edv[4] = b.x; edv[5] = b.y; edv[6] = b.z; edv[7] = b.w;
    }

    float acc0 = 0.f, acc1 = 0.f, lsum = 0.f;
    for (int j0 = 0; j0 < deg; j0 += 64) {
        // ---- phase 1: lane = edge slot; compute all 8 head-alphas ----
        int j = j0 + lane;
        int sp = (j < deg) ? adj[base + j] : 0;
        float4 ea = es4[sp * 2];
        float4 eb = es4[sp * 2 + 1];
        float ev[8] = {ea.x, ea.y, ea.z, ea.w, eb.x, eb.y, eb.z, eb.w};
        float p[8];
        #pragma unroll
        for (int hh = 0; hh < 8; hh++) {
            float v = ev[hh] + edv[hh];
            v = fmaxf(v, 0.2f * v);            // leaky relu
            float pe = __expf(v);              // bounded scores: no overflow
            p[hh] = (j < deg) ? pe : 0.f;
        }
        *(float4*)&alds[wid][lane * 12]     = make_float4(p[0], p[1], p[2], p[3]);
        *(float4*)&alds[wid][lane * 12 + 4] = make_float4(p[4], p[5], p[6], p[7]);
        slds[wid][lane] = sp;
        __builtin_amdgcn_s_waitcnt(0);         // drain lgkm (ds writes) before reads

        // ---- phase 2: lane = channel; walk edges, gather h ----
        int lim = min(64, deg - j0);
        for (int jj = 0; jj < lim; jj += 4) {
            int4 sv = *(const int4*)&slds[wid][jj];          // uniform b128
            float a0 = alds[wid][(jj + 0) * 12 + head];
            float a1 = alds[wid][(jj + 1) * 12 + head];
            float a2 = alds[wid][(jj + 2) * 12 + head];
            float a3 = alds[wid][(jj + 3) * 12 + head];
            unsigned int h0 = hb[sv.x * 64 + lane];
            unsigned int h1 = hb[sv.y * 64 + lane];
            unsigned int h2 = hb[sv.z * 64 + lane];
            unsigned int h3 = hb[sv.w * 64 + lane];
            lsum += (a0 + a1) + (a2 + a3);                   // alpha=0 pads tail
            acc0 += a0 * bflo2f(h0) + a1 * bflo2f(h1) + a2 * bflo2f(h2) + a3 * bflo2f(h3);
            acc1 += a0 * bfhi2f(h0) + a1 * bfhi2f(h1) + a2 * bfhi2f(h2) + a3 * bfhi2f(h3);
        }
    }

    float inv = 1.f / (lsum + 1e-16f);
    int ch = lane << 1;
    float o0 = acc0 * inv + ldf(bias, b_off + ch, isf32);
    float o1 = acc1 * inv + ldf(bias, b_off + ch + 1, isf32);
    o0 = o0 > 0.f ? o0 : (__expf(o0) - 1.f);
    o1 = o1 > 0.f ? o1 : (__expf(o1) - 1.f);
    *(float2*)(out + (size_t)node * GAT_F + ch) = make_float2(o0, o1);
}

// ---------- final FC ----------
__global__ __launch_bounds__(256) void k_fc(
    const float* __restrict__ h, const void* __restrict__ fw,
    const void* __restrict__ fb, void* __restrict__ out, int n,
    const int* __restrict__ flags)
{
    __shared__ float fws[GAT_F * GAT_C];
    int isf32 = flags[0];
    int t = threadIdx.x;
    for (int i = t; i < GAT_F * GAT_C; i += 256)
        fws[i] = ldf(fw, i, isf32);
    __syncthreads();
    int row = blockIdx.x * 256 + t;
    if (row >= n) return;
    float acc[16];
    #pragma unroll
    for (int c = 0; c < 16; c++) acc[c] = ldf(fb, c, isf32);
    const float4* hr = (const float4*)(h + (size_t)row * GAT_F);
    for (int k4 = 0; k4 < GAT_F / 4; k4++) {
        float4 xv = hr[k4];
        float xs4[4] = {xv.x, xv.y, xv.z, xv.w};
        #pragma unroll
        for (int kk = 0; kk < 4; kk++) {
            int k = k4 * 4 + kk;
            const float4* wr = (const float4*)(fws + k * GAT_C);
            #pragma unroll
            for (int c4 = 0; c4 < 4; c4++) {
                float4 wv = wr[c4];
                acc[c4 * 4 + 0] += xs4[kk] * wv.x;
                acc[c4 * 4 + 1] += xs4[kk] * wv.y;
                acc[c4 * 4 + 2] += xs4[kk] * wv.z;
                acc[c4 * 4 + 3] += xs4[kk] * wv.w;
            }
        }
    }
    if (isf32) {
        float* o = (float*)out + (size_t)row * GAT_C;
        #pragma unroll
        for (int c = 0; c < 16; c++) o[c] = acc[c];
    } else {
        __hip_bfloat16* o = (__hip_bfloat16*)out + (size_t)row * GAT_C;
        #pragma unroll
        for (int c = 0; c < 16; c++) o[c] = __float2bfloat16(acc[c]);
    }
}

extern "C" void kernel_launch(void* const* d_in, const int* in_sizes, int n_in,
                              void* d_out, int out_size, void* d_ws, size_t ws_size,
                              hipStream_t stream) {
    const void* x      = d_in[0];
    const void* Ws     = d_in[1];
    const void* att_s  = d_in[2];
    const void* att_d  = d_in[3];
    const void* biases = d_in[4];
    const void* fc_w   = d_in[5];
    const void* fc_b   = d_in[6];
    const int*  ei     = (const int*)d_in[7];

    const int N  = in_sizes[0] / GAT_F;
    const int E  = in_sizes[7] / 2;
    const int L  = in_sizes[1] / (GAT_F * GAT_F);
    const int ET = E + N;

    char* w = (char*)d_ws;
    int* flags         = (int*)w;            w += 64;
    float* hA          = (float*)w;          w += (size_t)N * GAT_F * 4;
    unsigned int* hB   = (unsigned int*)w;   w += (size_t)N * 64 * 4;
    float* es          = (float*)w;          w += (size_t)N * GAT_H * 4;
    float* ed          = (float*)w;          w += (size_t)N * GAT_H * 4;
    int* rowptr        = (int*)w;            w += (((size_t)(N + 1) * 4 + 15) & ~15ull);
    int* cursor        = (int*)w;            w += (size_t)N * 4;
    int* bsum          = (int*)w;            w += 1024 * 4;
    int* adj           = (int*)w;            w += (size_t)(ET + 16) * 4;
    unsigned short* wt = (unsigned short*)w; w += (size_t)L * 16384 * 2;
    unsigned short* wa = (unsigned short*)w; w += (size_t)L * 2048 * 2;

    int nb_n = (N + 255) / 256;
    int nb_e = (E + 255) / 256;
    int nb_s = (N + 1023) / 1024;

    k_detect<<<1, 256, 0, stream>>>((const unsigned short*)x, ei, flags);
    k_prep<<<L * 64 + L * 8, 256, 0, stream>>>(Ws, att_s, att_d, wt, wa, L, flags);

    k_init_deg<<<nb_n, 256, 0, stream>>>(cursor, N);
    k_count_deg<<<nb_e, 256, 0, stream>>>(ei, cursor, E, flags);
    k_scan_blk<<<nb_s, 256, 0, stream>>>(cursor, rowptr, bsum, N);
    k_scan_top<<<1, 256, 0, stream>>>(bsum, rowptr, nb_s, N);
    k_place_add<<<nb_n, 256, 0, stream>>>(rowptr, bsum, adj, cursor, N);
    k_scatter<<<nb_e, 256, 0, stream>>>(ei, rowptr, cursor, adj, E, flags);

    int nb_g = (N + 63) / 64;
    int nb_a = (N + 3) / 4;
    for (int l = 0; l < L; l++) {
        k_gemm_mfma<<<nb_g, 256, 0, stream>>>(
            (l == 0) ? x : (const void*)hA, (l == 0) ? 1 : 0,
            wt + (size_t)l * 16384, wa + (size_t)l * 2048,
            hB, es, ed, N, flags);
        k_aggregate<<<nb_a, 256, 0, stream>>>(
            hB, es, ed, rowptr, adj,
            biases, (long)l * GAT_F, hA, N, flags);
    }
    k_fc<<<nb_n, 256, 0, stream>>>(hA, fc_w, fc_b, d_out, N, flags);
}